// Round 8
// baseline (402.107 us; speedup 1.0000x reference)
//
#include <hip/hip_runtime.h>
#include <hip/hip_cooperative_groups.h>

namespace cg = cooperative_groups;

#define IN_F   360
#define HIDN   64
#define NCLS   5
#define BATCH  64
#define SEQ    128
#define NROWS  (BATCH*SEQ)   // 8192

// workspace layout (float offsets)
#define WS_FLAG  0
#define WS_WPACK 16
#define WS_WFAST 92176
#define WS_WT4   138256
#define WS_XEMB  162832
#define WS_GI    687120
#define WS_HC    3832848

#define LOG2E        1.4426950408889634f
#define NEG_HALF_L2E (-0.7213475204444817f)

__device__ __forceinline__ float fast_rcp(float x) { return __builtin_amdgcn_rcpf(x); }
__device__ __forceinline__ float fast_rsq(float x) { return __builtin_amdgcn_rsqf(x); }
__device__ __forceinline__ float sigmoid_(float x) {
    x = fminf(fmaxf(x, -60.0f), 60.0f);
    return fast_rcp(1.0f + exp2f(-LOG2E * x));
}
__device__ __forceinline__ float tanh_(float x) {
    x = fminf(fmaxf(x, -30.0f), 30.0f);
    float e = exp2f(-2.8853900817779268f * x);   // e^{-2x}
    return (1.0f - e) * fast_rcp(1.0f + e);
}
// __builtin_amdgcn_readlane is (int,int): bit-cast, never value-convert (R4/R6 bug)
__device__ __forceinline__ float readlane_f(float v, int l) {
    return __int_as_float(__builtin_amdgcn_readlane(__float_as_int(v), l));
}

struct Params {
    const float *x_seq, *scale, *trans, *ww, *bw;
    const float *bn_g, *bn_b, *bn_m, *bn_v, *ln_g, *ln_b;
    const float *wihf, *whhf, *bihf, *bhhf;
    const float *wihb, *whhb, *bihb, *bhhb;
    const float *fc1w, *fc1b, *fc2w, *fc2b;
    float *ws, *out;
};

// ONE cooperative kernel: prep -> wavkan -> gi -> gru -> head, grid.sync between.
// grid = 256 blocks x 256 threads (1 block/CU, co-resident by construction).
__global__ __launch_bounds__(256, 1) void fused_kernel(Params p) {
    cg::grid_group grid = cg::this_grid();
    __shared__ __align__(16) float smem[12672];   // 50688 B, max over phases
    int t = threadIdx.x, blk = blockIdx.x;
    float* ws = p.ws;

    // ================= P0: prep (flag pre-zeroed by memset node) =================
    {
        int idx = blk * 256 + t;                  // 65536 >= 47616: single pass
        float4* wpack  = (float4*)(ws + WS_WPACK);
        float2* wfast2 = (float2*)(ws + WS_WFAST);
        float*  wT4    = ws + WS_WT4;
        int*    flagp  = (int*)(ws + WS_FLAG);
        if (idx < 64 * IN_F) {
            int o = idx & 63, i = idx >> 6;
            float s  = p.scale[o * IN_F + i];
            float tr = p.trans[o * IN_F + i];
            if (s != 1.0f || tr != 0.0f) atomicOr(flagp, 1);
            float a  = 1.0f / s;
            float b  = -tr * a;
            float wq = 0.8673250705840776f * p.ww[o * IN_F + i];
            float bb = p.bw[o * IN_F + i];
            wpack[i * 64 + o] = make_float4(a, b, wq, bb);
            wfast2[(i >> 1) * 128 + o * 2 + (i & 1)] = make_float2(wq, bb);
        }
        int idx2 = idx - 64 * IN_F;
        if (idx2 >= 0 && idx2 < 24576) {
            int e = idx2 & 3; int rest = idx2 >> 2;
            int g = rest % 384; int k4 = rest / 384;
            int k = k4 * 4 + e; int dir = g / 192; int gg = g - dir * 192;
            const float* src = dir ? p.wihb : p.wihf;
            wT4[idx2] = src[gg * 64 + k];
        }
    }
    grid.sync();

    // ================= P1: WavKAN + BN + LN (512 tiles, 2 per block) =============
    {
        float2* xs_lds = (float2*)smem;           // 16*IN_F float2 = 46080 B
        int o = t & 63, grp = t >> 6;
        int fast = (*(const int*)(ws + WS_FLAG)) == 0;
        float* x_emb = ws + WS_XEMB;
        for (int it = 0; it < 2; ++it) {
            int row0 = (blk + 256 * it) * 16;
            float acc0 = 0.f, acc1 = 0.f, acc2 = 0.f, acc3 = 0.f;
            if (fast) {
                for (int idx = t; idx < 16 * IN_F; idx += 256) {
                    int r = idx / IN_F, i = idx - r * IN_F;
                    float x = p.x_seq[(row0 + r) * IN_F + i];
                    float u = x * x;
                    float phi = (u - 1.0f) * exp2f(u * NEG_HALF_L2E);
                    float sl  = x * fast_rcp(1.0f + exp2f(-LOG2E * x));
                    xs_lds[idx] = make_float2(phi, sl);
                }
                __syncthreads();
                const float4* wf4 = (const float4*)(ws + WS_WFAST);
                const float4* xs4 = (const float4*)xs_lds;
                const float4* xr0 = xs4 + (grp * 4 + 0) * 180;
                const float4* xr1 = xs4 + (grp * 4 + 1) * 180;
                const float4* xr2 = xs4 + (grp * 4 + 2) * 180;
                const float4* xr3 = xs4 + (grp * 4 + 3) * 180;
                #pragma unroll 2
                for (int i2 = 0; i2 < 180; ++i2) {
                    float4 wp = wf4[i2 * 64 + o];
                    float4 a = xr0[i2];
                    acc0 = fmaf(a.x, wp.x, acc0); acc0 = fmaf(a.y, wp.y, acc0);
                    acc0 = fmaf(a.z, wp.z, acc0); acc0 = fmaf(a.w, wp.w, acc0);
                    float4 b = xr1[i2];
                    acc1 = fmaf(b.x, wp.x, acc1); acc1 = fmaf(b.y, wp.y, acc1);
                    acc1 = fmaf(b.z, wp.z, acc1); acc1 = fmaf(b.w, wp.w, acc1);
                    float4 c = xr2[i2];
                    acc2 = fmaf(c.x, wp.x, acc2); acc2 = fmaf(c.y, wp.y, acc2);
                    acc2 = fmaf(c.z, wp.z, acc2); acc2 = fmaf(c.w, wp.w, acc2);
                    float4 d = xr3[i2];
                    acc3 = fmaf(d.x, wp.x, acc3); acc3 = fmaf(d.y, wp.y, acc3);
                    acc3 = fmaf(d.z, wp.z, acc3); acc3 = fmaf(d.w, wp.w, acc3);
                }
            } else {
                for (int idx = t; idx < 16 * IN_F; idx += 256) {
                    int r = idx / IN_F, i = idx - r * IN_F;
                    float x = p.x_seq[(row0 + r) * IN_F + i];
                    float sl = x * fast_rcp(1.0f + exp2f(-LOG2E * x));
                    xs_lds[idx] = make_float2(x, sl);
                }
                __syncthreads();
                const float4* wpack = (const float4*)(ws + WS_WPACK);
                const float2* xr0 = xs_lds + (grp * 4 + 0) * IN_F;
                const float2* xr1 = xs_lds + (grp * 4 + 1) * IN_F;
                const float2* xr2 = xs_lds + (grp * 4 + 2) * IN_F;
                const float2* xr3 = xs_lds + (grp * 4 + 3) * IN_F;
                for (int i = 0; i < IN_F; ++i) {
                    float4 wp = wpack[i * 64 + o];
                    {
                        float2 xs = xr0[i];
                        float xsc = fmaf(xs.x, wp.x, wp.y); float u = xsc * xsc;
                        float e = exp2f(u * NEG_HALF_L2E);
                        acc0 = fmaf((u - 1.0f) * e, wp.z, acc0);
                        acc0 = fmaf(xs.y, wp.w, acc0);
                    }
                    {
                        float2 xs = xr1[i];
                        float xsc = fmaf(xs.x, wp.x, wp.y); float u = xsc * xsc;
                        float e = exp2f(u * NEG_HALF_L2E);
                        acc1 = fmaf((u - 1.0f) * e, wp.z, acc1);
                        acc1 = fmaf(xs.y, wp.w, acc1);
                    }
                    {
                        float2 xs = xr2[i];
                        float xsc = fmaf(xs.x, wp.x, wp.y); float u = xsc * xsc;
                        float e = exp2f(u * NEG_HALF_L2E);
                        acc2 = fmaf((u - 1.0f) * e, wp.z, acc2);
                        acc2 = fmaf(xs.y, wp.w, acc2);
                    }
                    {
                        float2 xs = xr3[i];
                        float xsc = fmaf(xs.x, wp.x, wp.y); float u = xsc * xsc;
                        float e = exp2f(u * NEG_HALF_L2E);
                        acc3 = fmaf((u - 1.0f) * e, wp.z, acc3);
                        acc3 = fmaf(xs.y, wp.w, acc3);
                    }
                }
            }
            float bscale = p.bn_g[o] * fast_rsq(p.bn_v[o] + 1e-5f);
            float bshift = fmaf(-p.bn_m[o], bscale, p.bn_b[o]);
            float lg = p.ln_g[o], lb = p.ln_b[o];
            float vals[4] = {acc0, acc1, acc2, acc3};
            #pragma unroll
            for (int rr = 0; rr < 4; ++rr) {
                float y = fmaf(vals[rr], bscale, bshift);
                float s = y;
                #pragma unroll
                for (int m = 1; m < 64; m <<= 1) s += __shfl_xor(s, m, 64);
                float mu = s * (1.0f / 64.0f);
                float d = y - mu;
                float s2 = d * d;
                #pragma unroll
                for (int m = 1; m < 64; m <<= 1) s2 += __shfl_xor(s2, m, 64);
                float rstd = fast_rsq(s2 * (1.0f / 64.0f) + 1e-5f);
                x_emb[(row0 + grp * 4 + rr) * 64 + o] = fmaf(d * rstd, lg, lb);
            }
            __syncthreads();   // protect xs_lds reuse next iteration
        }
    }
    grid.sync();

    // ================= P2: gi = x_emb @ w_ihT + b_ih (32 rows/block) =============
    {
        float* xs = smem;                          // 2048 floats = 8 KB
        const float4* wT4   = (const float4*)(ws + WS_WT4);
        const float*  x_emb = ws + WS_XEMB;
        float* gi = ws + WS_GI;
        int row0 = blk * 32;
        {
            const float4* src = (const float4*)(x_emb + row0 * 64);
            float4* dst = (float4*)xs;
            dst[t] = src[t]; dst[t + 256] = src[t + 256];
        }
        int g1 = t;                                // gates t and 256+t (t<128)
        float bih1 = (g1 < 192) ? p.bihf[g1] : p.bihb[g1 - 192];
        float bih2 = (t < 128) ? p.bihb[64 + t] : 0.0f;   // g2-192 = 64+t
        float4 w1[16], w2[16];
        #pragma unroll
        for (int k4 = 0; k4 < 16; ++k4) w1[k4] = wT4[k4 * 384 + g1];
        if (t < 128) {
            #pragma unroll
            for (int k4 = 0; k4 < 16; ++k4) w2[k4] = wT4[k4 * 384 + 256 + t];
        }
        __syncthreads();
        for (int r = 0; r < 32; ++r) {
            const float4* x0 = (const float4*)(xs + r * 64);
            float a0 = bih1, a1 = 0.f;
            #pragma unroll
            for (int k4 = 0; k4 < 16; k4 += 2) {
                float4 xv = x0[k4];     float4 wv = w1[k4];
                a0 = fmaf(xv.x, wv.x, a0); a0 = fmaf(xv.y, wv.y, a0);
                a0 = fmaf(xv.z, wv.z, a0); a0 = fmaf(xv.w, wv.w, a0);
                float4 xu = x0[k4 + 1]; float4 wu = w1[k4 + 1];
                a1 = fmaf(xu.x, wu.x, a1); a1 = fmaf(xu.y, wu.y, a1);
                a1 = fmaf(xu.z, wu.z, a1); a1 = fmaf(xu.w, wu.w, a1);
            }
            gi[(row0 + r) * 384 + g1] = a0 + a1;
            if (t < 128) {
                float b0 = bih2, b1 = 0.f;
                #pragma unroll
                for (int k4 = 0; k4 < 16; k4 += 2) {
                    float4 xv = x0[k4];     float4 wv = w2[k4];
                    b0 = fmaf(xv.x, wv.x, b0); b0 = fmaf(xv.y, wv.y, b0);
                    b0 = fmaf(xv.z, wv.z, b0); b0 = fmaf(xv.w, wv.w, b0);
                    float4 xu = x0[k4 + 1]; float4 wu = w2[k4 + 1];
                    b1 = fmaf(xu.x, wu.x, b1); b1 = fmaf(xu.y, wu.y, b1);
                    b1 = fmaf(xu.z, wu.z, b1); b1 = fmaf(xu.w, wu.w, b1);
                }
                gi[(row0 + r) * 384 + 256 + t] = b0 + b1;
            }
        }
        __syncthreads();   // smem reused by gru phase
    }
    grid.sync();

    // ================= P3: GRU (R7 internals; blocks < 128; t<192 active) ========
    if (blk < 128) {
        float* gi_l = smem;                        // 64*192 floats = 48 KB
        float* ghb  = smem + 12288;                // 2*192 floats
        const float* gi = ws + WS_GI;
        int lane = t & 63;
        int b = blk & 63, dir = blk >> 6;
        const float* whh = dir ? p.whhb : p.whhf;
        const float* bhh = dir ? p.bhhb : p.bhhf;

        float w[64];
        float bias = 0.0f;
        float pf[64];
        float hreg = 0.0f;
        if (t < 192) {
            const float4* wrow = (const float4*)(whh + t * 64);
            #pragma unroll
            for (int q = 0; q < 16; ++q) {
                float4 a = wrow[q];
                w[4*q] = a.x; w[4*q+1] = a.y; w[4*q+2] = a.z; w[4*q+3] = a.w;
            }
            bias = bhh[t];
            const float* gsrc = gi + (size_t)(b * SEQ) * 384 + dir * 192 + t;
            #pragma unroll
            for (int q = 0; q < 64; ++q) {
                int sidx = dir ? (SEQ - 1 - q) : q;
                gi_l[q * 192 + t] = gsrc[sidx * 384];
            }
            #pragma unroll
            for (int q = 0; q < 64; ++q) {
                int sidx = dir ? (SEQ - 1 - (64 + q)) : (64 + q);
                pf[q] = gsrc[sidx * 384];
            }
        }
        __syncthreads();

        for (int ss = 0; ss < SEQ; ++ss) {
            if (ss == 64) {
                __syncthreads();
                if (t < 192) {
                    #pragma unroll
                    for (int q = 0; q < 64; ++q) gi_l[q * 192 + t] = pf[q];
                }
                __syncthreads();
            }
            int ssl = ss & 63;
            int pp = ss & 1;
            float ir = 0.f, iz = 0.f, in_ = 0.f;
            if (t < 192) {
                float a0 = bias, a1 = 0.f, a2 = 0.f, a3 = 0.f;
                #pragma unroll
                for (int k = 0; k < 64; k += 4) {
                    float h0 = readlane_f(hreg, k);
                    float h1 = readlane_f(hreg, k + 1);
                    float h2 = readlane_f(hreg, k + 2);
                    float h3 = readlane_f(hreg, k + 3);
                    a0 = fmaf(w[k],     h0, a0);
                    a1 = fmaf(w[k + 1], h1, a1);
                    a2 = fmaf(w[k + 2], h2, a2);
                    a3 = fmaf(w[k + 3], h3, a3);
                }
                ghb[pp * 192 + t] = (a0 + a1) + (a2 + a3);
                ir  = gi_l[ssl * 192 + lane];
                iz  = gi_l[ssl * 192 + 64 + lane];
                in_ = gi_l[ssl * 192 + 128 + lane];
            }
            __syncthreads();
            if (t < 192) {
                float r = sigmoid_(ir + ghb[pp * 192 + lane]);
                float z = sigmoid_(iz + ghb[pp * 192 + 64 + lane]);
                float n = tanh_(fmaf(r, ghb[pp * 192 + 128 + lane], in_));
                hreg = fmaf(z, hreg - n, n);       // (1-z)*n + z*h
            }
        }
        if (t < 64) (ws + WS_HC)[b * 128 + dir * 64 + lane] = hreg;
    }
    grid.sync();

    // ================= P4: classifier head (blocks < 64) =========================
    if (blk < 64) {
        float* hr = smem;            // 128
        float* h1 = smem + 128;      // 64
        const float* hc = ws + WS_HC;
        if (t < 128) hr[t] = hc[blk * 128 + t];
        __syncthreads();
        if (t < 64) {
            float acc = p.fc1b[t];
            const float4* w4 = (const float4*)(p.fc1w + t * 128);
            const float4* h4 = (const float4*)hr;
            #pragma unroll 8
            for (int k4 = 0; k4 < 32; ++k4) {
                float4 wv = w4[k4]; float4 hv = h4[k4];
                acc = fmaf(hv.x, wv.x, acc); acc = fmaf(hv.y, wv.y, acc);
                acc = fmaf(hv.z, wv.z, acc); acc = fmaf(hv.w, wv.w, acc);
            }
            h1[t] = fmaxf(acc, 0.0f);
        }
        __syncthreads();
        if (t < NCLS) {
            float acc2 = p.fc2b[t];
            const float* wr = p.fc2w + t * 64;
            #pragma unroll 8
            for (int k = 0; k < 64; ++k) acc2 = fmaf(h1[k], wr[k], acc2);
            p.out[blk * NCLS + t] = acc2;
        }
    }
}

extern "C" void kernel_launch(void* const* d_in, const int* in_sizes, int n_in,
                              void* d_out, int out_size, void* d_ws, size_t ws_size,
                              hipStream_t stream) {
    Params prm;
    prm.x_seq = (const float*)d_in[0];
    prm.scale = (const float*)d_in[1];
    prm.trans = (const float*)d_in[2];
    prm.ww    = (const float*)d_in[3];
    prm.bw    = (const float*)d_in[4];
    prm.bn_g  = (const float*)d_in[5];
    prm.bn_b  = (const float*)d_in[6];
    prm.bn_m  = (const float*)d_in[7];
    prm.bn_v  = (const float*)d_in[8];
    prm.ln_g  = (const float*)d_in[9];
    prm.ln_b  = (const float*)d_in[10];
    prm.wihf  = (const float*)d_in[11];
    prm.whhf  = (const float*)d_in[12];
    prm.bihf  = (const float*)d_in[13];
    prm.bhhf  = (const float*)d_in[14];
    prm.wihb  = (const float*)d_in[15];
    prm.whhb  = (const float*)d_in[16];
    prm.bihb  = (const float*)d_in[17];
    prm.bhhb  = (const float*)d_in[18];
    prm.fc1w  = (const float*)d_in[19];
    prm.fc1b  = (const float*)d_in[20];
    prm.fc2w  = (const float*)d_in[21];
    prm.fc2b  = (const float*)d_in[22];
    prm.ws    = (float*)d_ws;
    prm.out   = (float*)d_out;

    hipMemsetAsync((float*)d_ws + WS_FLAG, 0, sizeof(int), stream);
    void* args[] = { &prm };
    hipLaunchCooperativeKernel((void*)fused_kernel, dim3(256), dim3(256),
                               args, 0, stream);
}

// Round 9
// 282.149 us; speedup vs baseline: 1.4252x; 1.4252x over previous
//
#include <hip/hip_runtime.h>

#define IN_F   360
#define HIDN   64
#define NCLS   5
#define BATCH  64
#define SEQ    128
#define NROWS  (BATCH*SEQ)   // 8192

// workspace layout (float offsets)
#define WS_FLAG  0            // int flag: 0 => scale==1 && trans==0 everywhere (fast path ok)
#define WS_WPACK 16           // float4[360*64] (general path)
#define WS_WFAST 92176        // float2[360*64] (fast path packed {C*ww, bw})
#define WS_WT4   138256       // w_ih transposed, float4-packed
#define WS_XEMB  162832       // 8192*64
#define WS_GI    687120       // 8192*384
#define WS_HC    3832848      // 64*128

#define LOG2E        1.4426950408889634f
#define NEG_HALF_L2E (-0.7213475204444817f)

__device__ __forceinline__ float fast_rcp(float x) { return __builtin_amdgcn_rcpf(x); }
__device__ __forceinline__ float fast_rsq(float x) { return __builtin_amdgcn_rsqf(x); }
__device__ __forceinline__ float sigmoid_(float x) {
    x = fminf(fmaxf(x, -60.0f), 60.0f);
    return fast_rcp(1.0f + exp2f(-LOG2E * x));
}
__device__ __forceinline__ float tanh_(float x) {
    x = fminf(fmaxf(x, -30.0f), 30.0f);
    float e = exp2f(-2.8853900817779268f * x);   // e^{-2x}
    return (1.0f - e) * fast_rcp(1.0f + e);
}
// __builtin_amdgcn_readlane is (int,int): bit-cast, never value-convert (R4/R6 bug)
__device__ __forceinline__ float readlane_f(float v, int l) {
    return __int_as_float(__builtin_amdgcn_readlane(__float_as_int(v), l));
}

// ---------------- K0: weight prep + fast-path eligibility check ----------------
__global__ __launch_bounds__(256) void prep_kernel(
    const float* __restrict__ scale, const float* __restrict__ trans,
    const float* __restrict__ ww,    const float* __restrict__ bw,
    const float* __restrict__ wihf,  const float* __restrict__ wihb,
    float* __restrict__ ws) {
    int idx = blockIdx.x * 256 + threadIdx.x;
    float4* wpack  = (float4*)(ws + WS_WPACK);
    float2* wfast2 = (float2*)(ws + WS_WFAST);
    float*  wT4    = ws + WS_WT4;
    int*    flagp  = (int*)(ws + WS_FLAG);
    if (idx < 64 * IN_F) {
        int o = idx & 63, i = idx >> 6;
        float s  = scale[o * IN_F + i];
        float tr = trans[o * IN_F + i];
        if (s != 1.0f || tr != 0.0f) atomicOr(flagp, 1);
        float a  = 1.0f / s;
        float b  = -tr * a;
        float wq = 0.8673250705840776f * ww[o * IN_F + i];   // 2/(sqrt(3)*pi^0.25)
        float bb = bw[o * IN_F + i];
        wpack[i * 64 + o] = make_float4(a, b, wq, bb);
        wfast2[(i >> 1) * 128 + o * 2 + (i & 1)] = make_float2(wq, bb);
    }
    int idx2 = idx - 64 * IN_F;
    if (idx2 >= 0 && idx2 < 24576) {
        int e = idx2 & 3; int rest = idx2 >> 2;
        int g = rest % 384; int k4 = rest / 384;
        int k = k4 * 4 + e; int dir = g / 192; int gg = g - dir * 192;
        const float* src = dir ? wihb : wihf;
        wT4[idx2] = src[gg * 64 + k];
    }
}

// ---------------- K1: WavKAN + BatchNorm + LayerNorm ----------------
__global__ __launch_bounds__(256) void wavkan_kernel(
    const float* __restrict__ x_seq,
    const float* __restrict__ bn_g, const float* __restrict__ bn_b,
    const float* __restrict__ bn_m, const float* __restrict__ bn_v,
    const float* __restrict__ ln_g, const float* __restrict__ ln_b,
    const float* __restrict__ ws_c, float* __restrict__ x_emb) {
    __shared__ float2 xs_lds[16 * IN_F];   // 46 KB
    int t = threadIdx.x;
    int row0 = blockIdx.x * 16;
    int o = t & 63, grp = t >> 6;
    int fast = (*(const int*)(ws_c + WS_FLAG)) == 0;

    float acc0 = 0.f, acc1 = 0.f, acc2 = 0.f, acc3 = 0.f;

    if (fast) {
        for (int idx = t; idx < 16 * IN_F; idx += 256) {
            int r = idx / IN_F, i = idx - r * IN_F;
            float x = x_seq[(row0 + r) * IN_F + i];
            float u = x * x;
            float phi = (u - 1.0f) * exp2f(u * NEG_HALF_L2E);
            float sl  = x * fast_rcp(1.0f + exp2f(-LOG2E * x));
            xs_lds[idx] = make_float2(phi, sl);
        }
        __syncthreads();
        const float4* wf4 = (const float4*)(ws_c + WS_WFAST);
        const float4* xs4 = (const float4*)xs_lds;
        const float4* xr0 = xs4 + (grp * 4 + 0) * 180;
        const float4* xr1 = xs4 + (grp * 4 + 1) * 180;
        const float4* xr2 = xs4 + (grp * 4 + 2) * 180;
        const float4* xr3 = xs4 + (grp * 4 + 3) * 180;
        #pragma unroll 2
        for (int i2 = 0; i2 < 180; ++i2) {
            float4 wp = wf4[i2 * 64 + o];
            float4 a = xr0[i2];
            acc0 = fmaf(a.x, wp.x, acc0); acc0 = fmaf(a.y, wp.y, acc0);
            acc0 = fmaf(a.z, wp.z, acc0); acc0 = fmaf(a.w, wp.w, acc0);
            float4 b = xr1[i2];
            acc1 = fmaf(b.x, wp.x, acc1); acc1 = fmaf(b.y, wp.y, acc1);
            acc1 = fmaf(b.z, wp.z, acc1); acc1 = fmaf(b.w, wp.w, acc1);
            float4 c = xr2[i2];
            acc2 = fmaf(c.x, wp.x, acc2); acc2 = fmaf(c.y, wp.y, acc2);
            acc2 = fmaf(c.z, wp.z, acc2); acc2 = fmaf(c.w, wp.w, acc2);
            float4 d = xr3[i2];
            acc3 = fmaf(d.x, wp.x, acc3); acc3 = fmaf(d.y, wp.y, acc3);
            acc3 = fmaf(d.z, wp.z, acc3); acc3 = fmaf(d.w, wp.w, acc3);
        }
    } else {
        for (int idx = t; idx < 16 * IN_F; idx += 256) {
            int r = idx / IN_F, i = idx - r * IN_F;
            float x = x_seq[(row0 + r) * IN_F + i];
            float sl = x * fast_rcp(1.0f + exp2f(-LOG2E * x));
            xs_lds[idx] = make_float2(x, sl);
        }
        __syncthreads();
        const float4* wpack = (const float4*)(ws_c + WS_WPACK);
        const float2* xr0 = xs_lds + (grp * 4 + 0) * IN_F;
        const float2* xr1 = xs_lds + (grp * 4 + 1) * IN_F;
        const float2* xr2 = xs_lds + (grp * 4 + 2) * IN_F;
        const float2* xr3 = xs_lds + (grp * 4 + 3) * IN_F;
        for (int i = 0; i < IN_F; ++i) {
            float4 wp = wpack[i * 64 + o];
            {
                float2 xs = xr0[i];
                float xsc = fmaf(xs.x, wp.x, wp.y); float u = xsc * xsc;
                float e = exp2f(u * NEG_HALF_L2E);
                acc0 = fmaf((u - 1.0f) * e, wp.z, acc0);
                acc0 = fmaf(xs.y, wp.w, acc0);
            }
            {
                float2 xs = xr1[i];
                float xsc = fmaf(xs.x, wp.x, wp.y); float u = xsc * xsc;
                float e = exp2f(u * NEG_HALF_L2E);
                acc1 = fmaf((u - 1.0f) * e, wp.z, acc1);
                acc1 = fmaf(xs.y, wp.w, acc1);
            }
            {
                float2 xs = xr2[i];
                float xsc = fmaf(xs.x, wp.x, wp.y); float u = xsc * xsc;
                float e = exp2f(u * NEG_HALF_L2E);
                acc2 = fmaf((u - 1.0f) * e, wp.z, acc2);
                acc2 = fmaf(xs.y, wp.w, acc2);
            }
            {
                float2 xs = xr3[i];
                float xsc = fmaf(xs.x, wp.x, wp.y); float u = xsc * xsc;
                float e = exp2f(u * NEG_HALF_L2E);
                acc3 = fmaf((u - 1.0f) * e, wp.z, acc3);
                acc3 = fmaf(xs.y, wp.w, acc3);
            }
        }
    }

    float bscale = bn_g[o] * fast_rsq(bn_v[o] + 1e-5f);
    float bshift = fmaf(-bn_m[o], bscale, bn_b[o]);
    float lg = ln_g[o], lb = ln_b[o];
    float vals[4] = {acc0, acc1, acc2, acc3};
    #pragma unroll
    for (int rr = 0; rr < 4; ++rr) {
        float y = fmaf(vals[rr], bscale, bshift);
        float s = y;
        #pragma unroll
        for (int m = 1; m < 64; m <<= 1) s += __shfl_xor(s, m, 64);
        float mu = s * (1.0f / 64.0f);
        float d = y - mu;
        float s2 = d * d;
        #pragma unroll
        for (int m = 1; m < 64; m <<= 1) s2 += __shfl_xor(s2, m, 64);
        float rstd = fast_rsq(s2 * (1.0f / 64.0f) + 1e-5f);
        x_emb[(row0 + grp * 4 + rr) * 64 + o] = fmaf(d * rstd, lg, lb);
    }
}

// ---------------- K2: gi = x_emb @ w_ih^T + b_ih ----------------
__global__ __launch_bounds__(384) void gi_kernel(
    const float* __restrict__ ws_c,
    const float* __restrict__ bihf, const float* __restrict__ bihb,
    float* __restrict__ gi) {
    __shared__ __align__(16) float xs[32 * 64];   // 8 KB
    const float4* wT4   = (const float4*)(ws_c + WS_WT4);
    const float*  x_emb = ws_c + WS_XEMB;
    int t = threadIdx.x;
    int row0 = blockIdx.x * 32;
    {
        const float4* src = (const float4*)(x_emb + row0 * 64);
        float4* dst = (float4*)xs;
        for (int i = t; i < 512; i += 384) dst[i] = src[i];
    }
    int dir = t / 192, gg = t - dir * 192;
    float bih = dir ? bihb[gg] : bihf[gg];
    float4 w[16];
    #pragma unroll
    for (int k4 = 0; k4 < 16; ++k4) w[k4] = wT4[k4 * 384 + t];
    __syncthreads();
    for (int r = 0; r < 32; r += 2) {
        const float4* x0 = (const float4*)(xs + r * 64);
        const float4* x1 = (const float4*)(xs + r * 64 + 64);
        float a0 = bih, a1 = 0.f, b0 = bih, b1 = 0.f;
        #pragma unroll
        for (int k4 = 0; k4 < 16; k4 += 2) {
            float4 xv = x0[k4];     float4 wv = w[k4];
            a0 = fmaf(xv.x, wv.x, a0); a0 = fmaf(xv.y, wv.y, a0);
            a0 = fmaf(xv.z, wv.z, a0); a0 = fmaf(xv.w, wv.w, a0);
            float4 xu = x0[k4 + 1]; float4 wu = w[k4 + 1];
            a1 = fmaf(xu.x, wu.x, a1); a1 = fmaf(xu.y, wu.y, a1);
            a1 = fmaf(xu.z, wu.z, a1); a1 = fmaf(xu.w, wu.w, a1);
            float4 yv = x1[k4];
            b0 = fmaf(yv.x, wv.x, b0); b0 = fmaf(yv.y, wv.y, b0);
            b0 = fmaf(yv.z, wv.z, b0); b0 = fmaf(yv.w, wv.w, b0);
            float4 yu = x1[k4 + 1];
            b1 = fmaf(yu.x, wu.x, b1); b1 = fmaf(yu.y, wu.y, b1);
            b1 = fmaf(yu.z, wu.z, b1); b1 = fmaf(yu.w, wu.w, b1);
        }
        gi[(row0 + r) * 384 + t]     = a0 + a1;
        gi[(row0 + r + 1) * 384 + t] = b0 + b1;
    }
}

// ---------------- K3: bidirectional GRU — 2 chains/block, shared weights ----------------
// 64 blocks: dir = blk>>5, batches b0=(blk&31)*2, b0+1 (same dir => same W_hh).
// Thread t owns gate row t (w[64] regs) for BOTH chains; the two chains'
// readlane/fma streams interleave to hide the VALU->SGPR->VALU hazard, and one
// barrier + gh exchange serves both. gi staged in 32-step LDS windows (48 KB);
// next window prefetched into regs a full window (~25k cyc) ahead.
__global__ __launch_bounds__(192, 1) void gru_kernel(
    const float* __restrict__ ws_c,
    const float* __restrict__ whhf, const float* __restrict__ bhhf,
    const float* __restrict__ whhb, const float* __restrict__ bhhb,
    float* __restrict__ hc) {
    __shared__ __align__(16) float gi_l[32 * 384];   // 48 KB: [ssl][chain*192 + t]
    __shared__ float gh[2][384];
    const float* gi = ws_c + WS_GI;
    int t = threadIdx.x, lane = t & 63;
    int dir = blockIdx.x >> 5;
    int b0 = (blockIdx.x & 31) * 2, b1 = b0 + 1;
    const float* whh = dir ? whhb : whhf;
    const float* bhh = dir ? bhhb : bhhf;

    float w[64];
    {
        const float4* wrow = (const float4*)(whh + t * 64);
        #pragma unroll
        for (int q = 0; q < 16; ++q) {
            float4 a = wrow[q];
            w[4*q] = a.x; w[4*q+1] = a.y; w[4*q+2] = a.z; w[4*q+3] = a.w;
        }
    }
    float bias = bhh[t];

    const float* gsrc0 = gi + (size_t)(b0 * SEQ) * 384 + dir * 192 + t;
    const float* gsrc1 = gi + (size_t)(b1 * SEQ) * 384 + dir * 192 + t;

    // window 0 (steps 0..31) -> LDS
    #pragma unroll
    for (int q = 0; q < 32; ++q) {
        int sidx = dir ? (SEQ - 1 - q) : q;
        gi_l[q * 384 + t]       = gsrc0[sidx * 384];
        gi_l[q * 384 + 192 + t] = gsrc1[sidx * 384];
    }
    // window 1 (steps 32..63) -> regs
    float pf0[32], pf1[32];
    #pragma unroll
    for (int q = 0; q < 32; ++q) {
        int sidx = dir ? (SEQ - 1 - (32 + q)) : (32 + q);
        pf0[q] = gsrc0[sidx * 384];
        pf1[q] = gsrc1[sidx * 384];
    }
    float h0 = 0.0f, h1 = 0.0f;
    __syncthreads();

    for (int ss = 0; ss < SEQ; ++ss) {
        int ssl = ss & 31;
        if (ss != 0 && ssl == 0) {
            __syncthreads();                       // old-window reads complete
            #pragma unroll
            for (int q = 0; q < 32; ++q) {
                gi_l[q * 384 + t]       = pf0[q];
                gi_l[q * 384 + 192 + t] = pf1[q];
            }
            __syncthreads();                       // refill visible
            if (ss < 96) {                         // prefetch window ss/32 + 1
                #pragma unroll
                for (int q = 0; q < 32; ++q) {
                    int s_it = ss + 32 + q;
                    int sidx = dir ? (SEQ - 1 - s_it) : s_it;
                    pf0[q] = gsrc0[sidx * 384];
                    pf1[q] = gsrc1[sidx * 384];
                }
            }
        }
        // matvec, both chains interleaved (hazard hiding)
        float a0 = bias, a1 = 0.f, a2 = 0.f, a3 = 0.f;
        float c0 = bias, c1 = 0.f, c2 = 0.f, c3 = 0.f;
        #pragma unroll
        for (int k = 0; k < 64; k += 4) {
            float x0 = readlane_f(h0, k);
            float y0 = readlane_f(h1, k);
            float x1 = readlane_f(h0, k + 1);
            float y1 = readlane_f(h1, k + 1);
            float x2 = readlane_f(h0, k + 2);
            float y2 = readlane_f(h1, k + 2);
            float x3 = readlane_f(h0, k + 3);
            float y3 = readlane_f(h1, k + 3);
            a0 = fmaf(w[k],     x0, a0); c0 = fmaf(w[k],     y0, c0);
            a1 = fmaf(w[k + 1], x1, a1); c1 = fmaf(w[k + 1], y1, c1);
            a2 = fmaf(w[k + 2], x2, a2); c2 = fmaf(w[k + 2], y2, c2);
            a3 = fmaf(w[k + 3], x3, a3); c3 = fmaf(w[k + 3], y3, c3);
        }
        int pp = ss & 1;
        gh[pp][t]       = (a0 + a1) + (a2 + a3);
        gh[pp][192 + t] = (c0 + c1) + (c2 + c3);
        // consumer-side gi reads hoisted before the barrier (window only
        // mutated across barrier-separated refills)
        float ir0 = gi_l[ssl * 384 + lane];
        float iz0 = gi_l[ssl * 384 + 64 + lane];
        float in0 = gi_l[ssl * 384 + 128 + lane];
        float ir1 = gi_l[ssl * 384 + 192 + lane];
        float iz1 = gi_l[ssl * 384 + 256 + lane];
        float in1 = gi_l[ssl * 384 + 320 + lane];
        __syncthreads();
        float r0 = sigmoid_(ir0 + gh[pp][lane]);
        float z0 = sigmoid_(iz0 + gh[pp][64 + lane]);
        float n0 = tanh_(fmaf(r0, gh[pp][128 + lane], in0));
        h0 = fmaf(z0, h0 - n0, n0);
        float r1 = sigmoid_(ir1 + gh[pp][192 + lane]);
        float z1 = sigmoid_(iz1 + gh[pp][256 + lane]);
        float n1 = tanh_(fmaf(r1, gh[pp][320 + lane], in1));
        h1 = fmaf(z1, h1 - n1, n1);
    }
    if (t < 64) {
        hc[b0 * 128 + dir * 64 + lane] = h0;
        hc[b1 * 128 + dir * 64 + lane] = h1;
    }
}

// ---------------- K4: classifier head ----------------
__global__ __launch_bounds__(64) void head_kernel(
    const float* __restrict__ ws_c,
    const float* __restrict__ fc1w, const float* __restrict__ fc1b,
    const float* __restrict__ fc2w, const float* __restrict__ fc2b,
    float* __restrict__ out) {
    __shared__ __align__(16) float hr[128];
    __shared__ float h1[64];
    const float* hc = ws_c + WS_HC;
    int bb = blockIdx.x, t = threadIdx.x;
    hr[t]      = hc[bb * 128 + t];
    hr[64 + t] = hc[bb * 128 + 64 + t];
    __syncthreads();
    float acc = fc1b[t];
    const float4* w4 = (const float4*)(fc1w + t * 128);
    const float4* h4 = (const float4*)hr;
    #pragma unroll 8
    for (int k4 = 0; k4 < 32; ++k4) {
        float4 wv = w4[k4]; float4 hv = h4[k4];
        acc = fmaf(hv.x, wv.x, acc); acc = fmaf(hv.y, wv.y, acc);
        acc = fmaf(hv.z, wv.z, acc); acc = fmaf(hv.w, wv.w, acc);
    }
    h1[t] = fmaxf(acc, 0.0f);
    __syncthreads();
    if (t < NCLS) {
        float acc2 = fc2b[t];
        const float* wr = fc2w + t * 64;
        #pragma unroll 8
        for (int k = 0; k < 64; ++k) acc2 = fmaf(h1[k], wr[k], acc2);
        out[bb * NCLS + t] = acc2;
    }
}

extern "C" void kernel_launch(void* const* d_in, const int* in_sizes, int n_in,
                              void* d_out, int out_size, void* d_ws, size_t ws_size,
                              hipStream_t stream) {
    const float* x_seq = (const float*)d_in[0];
    const float* wscal = (const float*)d_in[1];
    const float* wtran = (const float*)d_in[2];
    const float* wwght = (const float*)d_in[3];
    const float* bwght = (const float*)d_in[4];
    const float* bn_g  = (const float*)d_in[5];
    const float* bn_b  = (const float*)d_in[6];
    const float* bn_m  = (const float*)d_in[7];
    const float* bn_v  = (const float*)d_in[8];
    const float* ln_g  = (const float*)d_in[9];
    const float* ln_b  = (const float*)d_in[10];
    const float* wihf  = (const float*)d_in[11];
    const float* whhf  = (const float*)d_in[12];
    const float* bihf  = (const float*)d_in[13];
    const float* bhhf  = (const float*)d_in[14];
    const float* wihb  = (const float*)d_in[15];
    const float* whhb  = (const float*)d_in[16];
    const float* bihb  = (const float*)d_in[17];
    const float* bhhb  = (const float*)d_in[18];
    const float* fc1w  = (const float*)d_in[19];
    const float* fc1b  = (const float*)d_in[20];
    const float* fc2w  = (const float*)d_in[21];
    const float* fc2b  = (const float*)d_in[22];
    float* ws  = (float*)d_ws;
    float* out = (float*)d_out;

    hipMemsetAsync(ws + WS_FLAG, 0, sizeof(int), stream);
    hipLaunchKernelGGL(prep_kernel, dim3(186), dim3(256), 0, stream,
                       wscal, wtran, wwght, bwght, wihf, wihb, ws);
    hipLaunchKernelGGL(wavkan_kernel, dim3(NROWS / 16), dim3(256), 0, stream,
                       x_seq, bn_g, bn_b, bn_m, bn_v, ln_g, ln_b, ws, ws + WS_XEMB);
    hipLaunchKernelGGL(gi_kernel, dim3(NROWS / 32), dim3(384), 0, stream,
                       ws, bihf, bihb, ws + WS_GI);
    hipLaunchKernelGGL(gru_kernel, dim3(64), dim3(192), 0, stream,
                       ws, whhf, bhhf, whhb, bhhb, ws + WS_HC);
    hipLaunchKernelGGL(head_kernel, dim3(64), dim3(64), 0, stream,
                       ws, fc1w, fc1b, fc2w, fc2b, out);
}

// Round 10
// 280.384 us; speedup vs baseline: 1.4341x; 1.0063x over previous
//
#include <hip/hip_runtime.h>

#define IN_F   360
#define HIDN   64
#define NCLS   5
#define BATCH  64
#define SEQ    128
#define NROWS  (BATCH*SEQ)   // 8192

// workspace layout (float offsets)
#define WS_FLAG  0            // int flag: 0 => scale==1 && trans==0 everywhere (fast path ok)
#define WS_WPACK 16           // float4[360*64] (general path)
#define WS_WFAST 92176        // float2[360*64] (fast path packed {C*ww, bw})
#define WS_WT4   138256       // w_ih transposed, float4-packed
#define WS_XEMB  162832       // 8192*64
#define WS_GI    687120       // 8192*384
#define WS_HC    3832848      // 64*128

#define LOG2E        1.4426950408889634f
#define NEG_HALF_L2E (-0.7213475204444817f)

__device__ __forceinline__ float fast_rcp(float x) { return __builtin_amdgcn_rcpf(x); }
__device__ __forceinline__ float fast_rsq(float x) { return __builtin_amdgcn_rsqf(x); }
__device__ __forceinline__ float sigmoid_(float x) {
    x = fminf(fmaxf(x, -60.0f), 60.0f);
    return fast_rcp(1.0f + exp2f(-LOG2E * x));
}
__device__ __forceinline__ float tanh_(float x) {
    x = fminf(fmaxf(x, -30.0f), 30.0f);
    float e = exp2f(-2.8853900817779268f * x);   // e^{-2x}
    return (1.0f - e) * fast_rcp(1.0f + e);
}
// __builtin_amdgcn_readlane is (int,int): bit-cast, never value-convert (R4/R6 bug)
__device__ __forceinline__ float readlane_f(float v, int l) {
    return __int_as_float(__builtin_amdgcn_readlane(__float_as_int(v), l));
}

// ---------------- K0: weight prep + fast-path eligibility check ----------------
__global__ __launch_bounds__(256) void prep_kernel(
    const float* __restrict__ scale, const float* __restrict__ trans,
    const float* __restrict__ ww,    const float* __restrict__ bw,
    const float* __restrict__ wihf,  const float* __restrict__ wihb,
    float* __restrict__ ws) {
    int idx = blockIdx.x * 256 + threadIdx.x;
    float4* wpack  = (float4*)(ws + WS_WPACK);
    float2* wfast2 = (float2*)(ws + WS_WFAST);
    float*  wT4    = ws + WS_WT4;
    int*    flagp  = (int*)(ws + WS_FLAG);
    if (idx < 64 * IN_F) {
        int o = idx & 63, i = idx >> 6;
        float s  = scale[o * IN_F + i];
        float tr = trans[o * IN_F + i];
        if (s != 1.0f || tr != 0.0f) atomicOr(flagp, 1);
        float a  = 1.0f / s;
        float b  = -tr * a;
        float wq = 0.8673250705840776f * ww[o * IN_F + i];   // 2/(sqrt(3)*pi^0.25)
        float bb = bw[o * IN_F + i];
        wpack[i * 64 + o] = make_float4(a, b, wq, bb);
        wfast2[(i >> 1) * 128 + o * 2 + (i & 1)] = make_float2(wq, bb);
    }
    int idx2 = idx - 64 * IN_F;
    if (idx2 >= 0 && idx2 < 24576) {
        int e = idx2 & 3; int rest = idx2 >> 2;
        int g = rest % 384; int k4 = rest / 384;
        int k = k4 * 4 + e; int dir = g / 192; int gg = g - dir * 192;
        const float* src = dir ? wihb : wihf;
        wT4[idx2] = src[gg * 64 + k];
    }
}

// ---------------- K1: WavKAN + BatchNorm + LayerNorm ----------------
__global__ __launch_bounds__(256) void wavkan_kernel(
    const float* __restrict__ x_seq,
    const float* __restrict__ bn_g, const float* __restrict__ bn_b,
    const float* __restrict__ bn_m, const float* __restrict__ bn_v,
    const float* __restrict__ ln_g, const float* __restrict__ ln_b,
    const float* __restrict__ ws_c, float* __restrict__ x_emb) {
    __shared__ float2 xs_lds[16 * IN_F];   // 46 KB
    int t = threadIdx.x;
    int row0 = blockIdx.x * 16;
    int o = t & 63, grp = t >> 6;
    int fast = (*(const int*)(ws_c + WS_FLAG)) == 0;

    float acc0 = 0.f, acc1 = 0.f, acc2 = 0.f, acc3 = 0.f;

    if (fast) {
        for (int idx = t; idx < 16 * IN_F; idx += 256) {
            int r = idx / IN_F, i = idx - r * IN_F;
            float x = x_seq[(row0 + r) * IN_F + i];
            float u = x * x;
            float phi = (u - 1.0f) * exp2f(u * NEG_HALF_L2E);
            float sl  = x * fast_rcp(1.0f + exp2f(-LOG2E * x));
            xs_lds[idx] = make_float2(phi, sl);
        }
        __syncthreads();
        const float4* wf4 = (const float4*)(ws_c + WS_WFAST);
        const float4* xs4 = (const float4*)xs_lds;
        const float4* xr0 = xs4 + (grp * 4 + 0) * 180;
        const float4* xr1 = xs4 + (grp * 4 + 1) * 180;
        const float4* xr2 = xs4 + (grp * 4 + 2) * 180;
        const float4* xr3 = xs4 + (grp * 4 + 3) * 180;
        #pragma unroll 2
        for (int i2 = 0; i2 < 180; ++i2) {
            float4 wp = wf4[i2 * 64 + o];
            float4 a = xr0[i2];
            acc0 = fmaf(a.x, wp.x, acc0); acc0 = fmaf(a.y, wp.y, acc0);
            acc0 = fmaf(a.z, wp.z, acc0); acc0 = fmaf(a.w, wp.w, acc0);
            float4 b = xr1[i2];
            acc1 = fmaf(b.x, wp.x, acc1); acc1 = fmaf(b.y, wp.y, acc1);
            acc1 = fmaf(b.z, wp.z, acc1); acc1 = fmaf(b.w, wp.w, acc1);
            float4 c = xr2[i2];
            acc2 = fmaf(c.x, wp.x, acc2); acc2 = fmaf(c.y, wp.y, acc2);
            acc2 = fmaf(c.z, wp.z, acc2); acc2 = fmaf(c.w, wp.w, acc2);
            float4 d = xr3[i2];
            acc3 = fmaf(d.x, wp.x, acc3); acc3 = fmaf(d.y, wp.y, acc3);
            acc3 = fmaf(d.z, wp.z, acc3); acc3 = fmaf(d.w, wp.w, acc3);
        }
    } else {
        for (int idx = t; idx < 16 * IN_F; idx += 256) {
            int r = idx / IN_F, i = idx - r * IN_F;
            float x = x_seq[(row0 + r) * IN_F + i];
            float sl = x * fast_rcp(1.0f + exp2f(-LOG2E * x));
            xs_lds[idx] = make_float2(x, sl);
        }
        __syncthreads();
        const float4* wpack = (const float4*)(ws_c + WS_WPACK);
        const float2* xr0 = xs_lds + (grp * 4 + 0) * IN_F;
        const float2* xr1 = xs_lds + (grp * 4 + 1) * IN_F;
        const float2* xr2 = xs_lds + (grp * 4 + 2) * IN_F;
        const float2* xr3 = xs_lds + (grp * 4 + 3) * IN_F;
        for (int i = 0; i < IN_F; ++i) {
            float4 wp = wpack[i * 64 + o];
            {
                float2 xs = xr0[i];
                float xsc = fmaf(xs.x, wp.x, wp.y); float u = xsc * xsc;
                float e = exp2f(u * NEG_HALF_L2E);
                acc0 = fmaf((u - 1.0f) * e, wp.z, acc0);
                acc0 = fmaf(xs.y, wp.w, acc0);
            }
            {
                float2 xs = xr1[i];
                float xsc = fmaf(xs.x, wp.x, wp.y); float u = xsc * xsc;
                float e = exp2f(u * NEG_HALF_L2E);
                acc1 = fmaf((u - 1.0f) * e, wp.z, acc1);
                acc1 = fmaf(xs.y, wp.w, acc1);
            }
            {
                float2 xs = xr2[i];
                float xsc = fmaf(xs.x, wp.x, wp.y); float u = xsc * xsc;
                float e = exp2f(u * NEG_HALF_L2E);
                acc2 = fmaf((u - 1.0f) * e, wp.z, acc2);
                acc2 = fmaf(xs.y, wp.w, acc2);
            }
            {
                float2 xs = xr3[i];
                float xsc = fmaf(xs.x, wp.x, wp.y); float u = xsc * xsc;
                float e = exp2f(u * NEG_HALF_L2E);
                acc3 = fmaf((u - 1.0f) * e, wp.z, acc3);
                acc3 = fmaf(xs.y, wp.w, acc3);
            }
        }
    }

    float bscale = bn_g[o] * fast_rsq(bn_v[o] + 1e-5f);
    float bshift = fmaf(-bn_m[o], bscale, bn_b[o]);
    float lg = ln_g[o], lb = ln_b[o];
    float vals[4] = {acc0, acc1, acc2, acc3};
    #pragma unroll
    for (int rr = 0; rr < 4; ++rr) {
        float y = fmaf(vals[rr], bscale, bshift);
        float s = y;
        #pragma unroll
        for (int m = 1; m < 64; m <<= 1) s += __shfl_xor(s, m, 64);
        float mu = s * (1.0f / 64.0f);
        float d = y - mu;
        float s2 = d * d;
        #pragma unroll
        for (int m = 1; m < 64; m <<= 1) s2 += __shfl_xor(s2, m, 64);
        float rstd = fast_rsq(s2 * (1.0f / 64.0f) + 1e-5f);
        x_emb[(row0 + grp * 4 + rr) * 64 + o] = fmaf(d * rstd, lg, lb);
    }
}

// ---------------- K2: gi = x_emb @ w_ih^T + b_ih ----------------
__global__ __launch_bounds__(384) void gi_kernel(
    const float* __restrict__ ws_c,
    const float* __restrict__ bihf, const float* __restrict__ bihb,
    float* __restrict__ gi) {
    __shared__ __align__(16) float xs[32 * 64];   // 8 KB
    const float4* wT4   = (const float4*)(ws_c + WS_WT4);
    const float*  x_emb = ws_c + WS_XEMB;
    int t = threadIdx.x;
    int row0 = blockIdx.x * 32;
    {
        const float4* src = (const float4*)(x_emb + row0 * 64);
        float4* dst = (float4*)xs;
        for (int i = t; i < 512; i += 384) dst[i] = src[i];
    }
    int dir = t / 192, gg = t - dir * 192;
    float bih = dir ? bihb[gg] : bihf[gg];
    float4 w[16];
    #pragma unroll
    for (int k4 = 0; k4 < 16; ++k4) w[k4] = wT4[k4 * 384 + t];
    __syncthreads();
    for (int r = 0; r < 32; r += 2) {
        const float4* x0 = (const float4*)(xs + r * 64);
        const float4* x1 = (const float4*)(xs + r * 64 + 64);
        float a0 = bih, a1 = 0.f, b0 = bih, b1 = 0.f;
        #pragma unroll
        for (int k4 = 0; k4 < 16; k4 += 2) {
            float4 xv = x0[k4];     float4 wv = w[k4];
            a0 = fmaf(xv.x, wv.x, a0); a0 = fmaf(xv.y, wv.y, a0);
            a0 = fmaf(xv.z, wv.z, a0); a0 = fmaf(xv.w, wv.w, a0);
            float4 xu = x0[k4 + 1]; float4 wu = w[k4 + 1];
            a1 = fmaf(xu.x, wu.x, a1); a1 = fmaf(xu.y, wu.y, a1);
            a1 = fmaf(xu.z, wu.z, a1); a1 = fmaf(xu.w, wu.w, a1);
            float4 yv = x1[k4];
            b0 = fmaf(yv.x, wv.x, b0); b0 = fmaf(yv.y, wv.y, b0);
            b0 = fmaf(yv.z, wv.z, b0); b0 = fmaf(yv.w, wv.w, b0);
            float4 yu = x1[k4 + 1];
            b1 = fmaf(yu.x, wu.x, b1); b1 = fmaf(yu.y, wu.y, b1);
            b1 = fmaf(yu.z, wu.z, b1); b1 = fmaf(yu.w, wu.w, b1);
        }
        gi[(row0 + r) * 384 + t]     = a0 + a1;
        gi[(row0 + r + 1) * 384 + t] = b0 + b1;
    }
}

// ---------------- K3: bidirectional GRU — 2 chains/block, NO prefetch registers ----------------
// 64 blocks: dir = blk>>5, batches b0=(blk&31)*2, b0+1 (same dir => shared w[64] regs).
// R9's spill trigger (pf register windows) removed: gi staged in 32-step LDS
// windows refilled DIRECTLY global->LDS at window boundaries (burst ~1-2k cyc
// per 32 steps, off the serial chain). VGPR footprint = R7's (~92). The two
// chains' readlane/fma streams interleave to fill R7's ~700 cyc/step of
// hazard/barrier stall; one barrier + one gh exchange serves both chains.
__global__ __launch_bounds__(192, 1) void gru_kernel(
    const float* __restrict__ ws_c,
    const float* __restrict__ whhf, const float* __restrict__ bhhf,
    const float* __restrict__ whhb, const float* __restrict__ bhhb,
    float* __restrict__ hc) {
    __shared__ __align__(16) float gi_l[32 * 384];   // 48 KB: [ssl][chain*192 + t]
    __shared__ float gh[2][384];
    const float* gi = ws_c + WS_GI;
    int t = threadIdx.x, lane = t & 63;
    int dir = blockIdx.x >> 5;
    int b0 = (blockIdx.x & 31) * 2, b1 = b0 + 1;
    const float* whh = dir ? whhb : whhf;
    const float* bhh = dir ? bhhb : bhhf;

    float w[64];
    {
        const float4* wrow = (const float4*)(whh + t * 64);
        #pragma unroll
        for (int q = 0; q < 16; ++q) {
            float4 a = wrow[q];
            w[4*q] = a.x; w[4*q+1] = a.y; w[4*q+2] = a.z; w[4*q+3] = a.w;
        }
    }
    float bias = bhh[t];

    const float* gsrc0 = gi + (size_t)(b0 * SEQ) * 384 + dir * 192 + t;
    const float* gsrc1 = gi + (size_t)(b1 * SEQ) * 384 + dir * 192 + t;

    // window 0 (steps 0..31) -> LDS
    #pragma unroll 8
    for (int q = 0; q < 32; ++q) {
        int sidx = dir ? (SEQ - 1 - q) : q;
        gi_l[q * 384 + t]       = gsrc0[sidx * 384];
        gi_l[q * 384 + 192 + t] = gsrc1[sidx * 384];
    }
    float h0 = 0.0f, h1 = 0.0f;
    __syncthreads();

    for (int ss = 0; ss < SEQ; ++ss) {
        int ssl = ss & 31;
        if (ss != 0 && ssl == 0) {
            __syncthreads();                       // old-window reads complete
            #pragma unroll 8
            for (int q = 0; q < 32; ++q) {         // direct global->LDS refill
                int s_it = ss + q;
                int sidx = dir ? (SEQ - 1 - s_it) : s_it;
                gi_l[q * 384 + t]       = gsrc0[sidx * 384];
                gi_l[q * 384 + 192 + t] = gsrc1[sidx * 384];
            }
            __syncthreads();                       // refill visible
        }
        // matvec, both chains interleaved (fills readlane->fma hazard slots)
        float a0 = bias, a1 = 0.f, a2 = 0.f, a3 = 0.f;
        float c0 = bias, c1 = 0.f, c2 = 0.f, c3 = 0.f;
        #pragma unroll
        for (int k = 0; k < 64; k += 4) {
            float x0 = readlane_f(h0, k);
            float y0 = readlane_f(h1, k);
            float x1 = readlane_f(h0, k + 1);
            float y1 = readlane_f(h1, k + 1);
            float x2 = readlane_f(h0, k + 2);
            float y2 = readlane_f(h1, k + 2);
            float x3 = readlane_f(h0, k + 3);
            float y3 = readlane_f(h1, k + 3);
            a0 = fmaf(w[k],     x0, a0); c0 = fmaf(w[k],     y0, c0);
            a1 = fmaf(w[k + 1], x1, a1); c1 = fmaf(w[k + 1], y1, c1);
            a2 = fmaf(w[k + 2], x2, a2); c2 = fmaf(w[k + 2], y2, c2);
            a3 = fmaf(w[k + 3], x3, a3); c3 = fmaf(w[k + 3], y3, c3);
        }
        int pp = ss & 1;
        gh[pp][t]       = (a0 + a1) + (a2 + a3);
        gh[pp][192 + t] = (c0 + c1) + (c2 + c3);
        // consumer-side gi reads hoisted before the barrier (window only
        // mutated across barrier-separated refills)
        float ir0 = gi_l[ssl * 384 + lane];
        float iz0 = gi_l[ssl * 384 + 64 + lane];
        float in0 = gi_l[ssl * 384 + 128 + lane];
        float ir1 = gi_l[ssl * 384 + 192 + lane];
        float iz1 = gi_l[ssl * 384 + 256 + lane];
        float in1 = gi_l[ssl * 384 + 320 + lane];
        __syncthreads();
        float r0 = sigmoid_(ir0 + gh[pp][lane]);
        float z0 = sigmoid_(iz0 + gh[pp][64 + lane]);
        float n0 = tanh_(fmaf(r0, gh[pp][128 + lane], in0));
        h0 = fmaf(z0, h0 - n0, n0);
        float r1 = sigmoid_(ir1 + gh[pp][192 + lane]);
        float z1 = sigmoid_(iz1 + gh[pp][256 + lane]);
        float n1 = tanh_(fmaf(r1, gh[pp][320 + lane], in1));
        h1 = fmaf(z1, h1 - n1, n1);
    }
    if (t < 64) {
        hc[b0 * 128 + dir * 64 + lane] = h0;
        hc[b1 * 128 + dir * 64 + lane] = h1;
    }
}

// ---------------- K4: classifier head ----------------
__global__ __launch_bounds__(64) void head_kernel(
    const float* __restrict__ ws_c,
    const float* __restrict__ fc1w, const float* __restrict__ fc1b,
    const float* __restrict__ fc2w, const float* __restrict__ fc2b,
    float* __restrict__ out) {
    __shared__ __align__(16) float hr[128];
    __shared__ float h1[64];
    const float* hc = ws_c + WS_HC;
    int bb = blockIdx.x, t = threadIdx.x;
    hr[t]      = hc[bb * 128 + t];
    hr[64 + t] = hc[bb * 128 + 64 + t];
    __syncthreads();
    float acc = fc1b[t];
    const float4* w4 = (const float4*)(fc1w + t * 128);
    const float4* h4 = (const float4*)hr;
    #pragma unroll 8
    for (int k4 = 0; k4 < 32; ++k4) {
        float4 wv = w4[k4]; float4 hv = h4[k4];
        acc = fmaf(hv.x, wv.x, acc); acc = fmaf(hv.y, wv.y, acc);
        acc = fmaf(hv.z, wv.z, acc); acc = fmaf(hv.w, wv.w, acc);
    }
    h1[t] = fmaxf(acc, 0.0f);
    __syncthreads();
    if (t < NCLS) {
        float acc2 = fc2b[t];
        const float* wr = fc2w + t * 64;
        #pragma unroll 8
        for (int k = 0; k < 64; ++k) acc2 = fmaf(h1[k], wr[k], acc2);
        out[bb * NCLS + t] = acc2;
    }
}

extern "C" void kernel_launch(void* const* d_in, const int* in_sizes, int n_in,
                              void* d_out, int out_size, void* d_ws, size_t ws_size,
                              hipStream_t stream) {
    const float* x_seq = (const float*)d_in[0];
    const float* wscal = (const float*)d_in[1];
    const float* wtran = (const float*)d_in[2];
    const float* wwght = (const float*)d_in[3];
    const float* bwght = (const float*)d_in[4];
    const float* bn_g  = (const float*)d_in[5];
    const float* bn_b  = (const float*)d_in[6];
    const float* bn_m  = (const float*)d_in[7];
    const float* bn_v  = (const float*)d_in[8];
    const float* ln_g  = (const float*)d_in[9];
    const float* ln_b  = (const float*)d_in[10];
    const float* wihf  = (const float*)d_in[11];
    const float* whhf  = (const float*)d_in[12];
    const float* bihf  = (const float*)d_in[13];
    const float* bhhf  = (const float*)d_in[14];
    const float* wihb  = (const float*)d_in[15];
    const float* whhb  = (const float*)d_in[16];
    const float* bihb  = (const float*)d_in[17];
    const float* bhhb  = (const float*)d_in[18];
    const float* fc1w  = (const float*)d_in[19];
    const float* fc1b  = (const float*)d_in[20];
    const float* fc2w  = (const float*)d_in[21];
    const float* fc2b  = (const float*)d_in[22];
    float* ws  = (float*)d_ws;
    float* out = (float*)d_out;

    hipMemsetAsync(ws + WS_FLAG, 0, sizeof(int), stream);
    hipLaunchKernelGGL(prep_kernel, dim3(186), dim3(256), 0, stream,
                       wscal, wtran, wwght, bwght, wihf, wihb, ws);
    hipLaunchKernelGGL(wavkan_kernel, dim3(NROWS / 16), dim3(256), 0, stream,
                       x_seq, bn_g, bn_b, bn_m, bn_v, ln_g, ln_b, ws, ws + WS_XEMB);
    hipLaunchKernelGGL(gi_kernel, dim3(NROWS / 32), dim3(384), 0, stream,
                       ws, bihf, bihb, ws + WS_GI);
    hipLaunchKernelGGL(gru_kernel, dim3(64), dim3(192), 0, stream,
                       ws, whhf, bhhf, whhb, bhhb, ws + WS_HC);
    hipLaunchKernelGGL(head_kernel, dim3(64), dim3(64), 0, stream,
                       ws, fc1w, fc1b, fc2w, fc2b, out);
}

// Round 11
// 279.900 us; speedup vs baseline: 1.4366x; 1.0017x over previous
//
#include <hip/hip_runtime.h>

#define IN_F   360
#define HIDN   64
#define NCLS   5
#define BATCH  64
#define SEQ    128
#define NROWS  (BATCH*SEQ)   // 8192

// workspace layout (float offsets)
#define WS_FLAG  0            // int flag: 0 => scale==1 && trans==0 everywhere (fast path ok)
#define WS_WPACK 16           // float4[360*64] (general path)
#define WS_WFAST 92176        // float2[360*64] (fast path packed {C*ww, bw})
#define WS_WT4   138256       // w_ih transposed, float4-packed
#define WS_XEMB  162832       // 8192*64
#define WS_GI    687120       // 8192*384
#define WS_HC    3832848      // 64*128

#define LOG2E        1.4426950408889634f
#define NEG_HALF_L2E (-0.7213475204444817f)

__device__ __forceinline__ float fast_rcp(float x) { return __builtin_amdgcn_rcpf(x); }
__device__ __forceinline__ float fast_rsq(float x) { return __builtin_amdgcn_rsqf(x); }
__device__ __forceinline__ float sigmoid_(float x) {
    x = fminf(fmaxf(x, -60.0f), 60.0f);
    return fast_rcp(1.0f + exp2f(-LOG2E * x));
}
__device__ __forceinline__ float tanh_(float x) {
    x = fminf(fmaxf(x, -30.0f), 30.0f);
    float e = exp2f(-2.8853900817779268f * x);   // e^{-2x}
    return (1.0f - e) * fast_rcp(1.0f + e);
}
// __builtin_amdgcn_readlane is (int,int): bit-cast, never value-convert (R4/R6 bug)
__device__ __forceinline__ float readlane_f(float v, int l) {
    return __int_as_float(__builtin_amdgcn_readlane(__float_as_int(v), l));
}

// ---------------- K0: weight prep + fast-path eligibility check ----------------
__global__ __launch_bounds__(256) void prep_kernel(
    const float* __restrict__ scale, const float* __restrict__ trans,
    const float* __restrict__ ww,    const float* __restrict__ bw,
    const float* __restrict__ wihf,  const float* __restrict__ wihb,
    float* __restrict__ ws) {
    int idx = blockIdx.x * 256 + threadIdx.x;
    float4* wpack  = (float4*)(ws + WS_WPACK);
    float2* wfast2 = (float2*)(ws + WS_WFAST);
    float*  wT4    = ws + WS_WT4;
    int*    flagp  = (int*)(ws + WS_FLAG);
    if (idx < 64 * IN_F) {
        int o = idx & 63, i = idx >> 6;
        float s  = scale[o * IN_F + i];
        float tr = trans[o * IN_F + i];
        if (s != 1.0f || tr != 0.0f) atomicOr(flagp, 1);
        float a  = 1.0f / s;
        float b  = -tr * a;
        float wq = 0.8673250705840776f * ww[o * IN_F + i];   // 2/(sqrt(3)*pi^0.25)
        float bb = bw[o * IN_F + i];
        wpack[i * 64 + o] = make_float4(a, b, wq, bb);
        wfast2[(i >> 1) * 128 + o * 2 + (i & 1)] = make_float2(wq, bb);
    }
    int idx2 = idx - 64 * IN_F;
    if (idx2 >= 0 && idx2 < 24576) {
        int e = idx2 & 3; int rest = idx2 >> 2;
        int g = rest % 384; int k4 = rest / 384;
        int k = k4 * 4 + e; int dir = g / 192; int gg = g - dir * 192;
        const float* src = dir ? wihb : wihf;
        wT4[idx2] = src[gg * 64 + k];
    }
}

// ---------------- K1: WavKAN + BatchNorm + LayerNorm ----------------
__global__ __launch_bounds__(256) void wavkan_kernel(
    const float* __restrict__ x_seq,
    const float* __restrict__ bn_g, const float* __restrict__ bn_b,
    const float* __restrict__ bn_m, const float* __restrict__ bn_v,
    const float* __restrict__ ln_g, const float* __restrict__ ln_b,
    const float* __restrict__ ws_c, float* __restrict__ x_emb) {
    __shared__ float2 xs_lds[16 * IN_F];   // 46 KB
    int t = threadIdx.x;
    int row0 = blockIdx.x * 16;
    int o = t & 63, grp = t >> 6;
    int fast = (*(const int*)(ws_c + WS_FLAG)) == 0;

    float acc0 = 0.f, acc1 = 0.f, acc2 = 0.f, acc3 = 0.f;

    if (fast) {
        for (int idx = t; idx < 16 * IN_F; idx += 256) {
            int r = idx / IN_F, i = idx - r * IN_F;
            float x = x_seq[(row0 + r) * IN_F + i];
            float u = x * x;
            float phi = (u - 1.0f) * exp2f(u * NEG_HALF_L2E);
            float sl  = x * fast_rcp(1.0f + exp2f(-LOG2E * x));
            xs_lds[idx] = make_float2(phi, sl);
        }
        __syncthreads();
        const float4* wf4 = (const float4*)(ws_c + WS_WFAST);
        const float4* xs4 = (const float4*)xs_lds;
        const float4* xr0 = xs4 + (grp * 4 + 0) * 180;
        const float4* xr1 = xs4 + (grp * 4 + 1) * 180;
        const float4* xr2 = xs4 + (grp * 4 + 2) * 180;
        const float4* xr3 = xs4 + (grp * 4 + 3) * 180;
        #pragma unroll 2
        for (int i2 = 0; i2 < 180; ++i2) {
            float4 wp = wf4[i2 * 64 + o];
            float4 a = xr0[i2];
            acc0 = fmaf(a.x, wp.x, acc0); acc0 = fmaf(a.y, wp.y, acc0);
            acc0 = fmaf(a.z, wp.z, acc0); acc0 = fmaf(a.w, wp.w, acc0);
            float4 b = xr1[i2];
            acc1 = fmaf(b.x, wp.x, acc1); acc1 = fmaf(b.y, wp.y, acc1);
            acc1 = fmaf(b.z, wp.z, acc1); acc1 = fmaf(b.w, wp.w, acc1);
            float4 c = xr2[i2];
            acc2 = fmaf(c.x, wp.x, acc2); acc2 = fmaf(c.y, wp.y, acc2);
            acc2 = fmaf(c.z, wp.z, acc2); acc2 = fmaf(c.w, wp.w, acc2);
            float4 d = xr3[i2];
            acc3 = fmaf(d.x, wp.x, acc3); acc3 = fmaf(d.y, wp.y, acc3);
            acc3 = fmaf(d.z, wp.z, acc3); acc3 = fmaf(d.w, wp.w, acc3);
        }
    } else {
        for (int idx = t; idx < 16 * IN_F; idx += 256) {
            int r = idx / IN_F, i = idx - r * IN_F;
            float x = x_seq[(row0 + r) * IN_F + i];
            float sl = x * fast_rcp(1.0f + exp2f(-LOG2E * x));
            xs_lds[idx] = make_float2(x, sl);
        }
        __syncthreads();
        const float4* wpack = (const float4*)(ws_c + WS_WPACK);
        const float2* xr0 = xs_lds + (grp * 4 + 0) * IN_F;
        const float2* xr1 = xs_lds + (grp * 4 + 1) * IN_F;
        const float2* xr2 = xs_lds + (grp * 4 + 2) * IN_F;
        const float2* xr3 = xs_lds + (grp * 4 + 3) * IN_F;
        for (int i = 0; i < IN_F; ++i) {
            float4 wp = wpack[i * 64 + o];
            {
                float2 xs = xr0[i];
                float xsc = fmaf(xs.x, wp.x, wp.y); float u = xsc * xsc;
                float e = exp2f(u * NEG_HALF_L2E);
                acc0 = fmaf((u - 1.0f) * e, wp.z, acc0);
                acc0 = fmaf(xs.y, wp.w, acc0);
            }
            {
                float2 xs = xr1[i];
                float xsc = fmaf(xs.x, wp.x, wp.y); float u = xsc * xsc;
                float e = exp2f(u * NEG_HALF_L2E);
                acc1 = fmaf((u - 1.0f) * e, wp.z, acc1);
                acc1 = fmaf(xs.y, wp.w, acc1);
            }
            {
                float2 xs = xr2[i];
                float xsc = fmaf(xs.x, wp.x, wp.y); float u = xsc * xsc;
                float e = exp2f(u * NEG_HALF_L2E);
                acc2 = fmaf((u - 1.0f) * e, wp.z, acc2);
                acc2 = fmaf(xs.y, wp.w, acc2);
            }
            {
                float2 xs = xr3[i];
                float xsc = fmaf(xs.x, wp.x, wp.y); float u = xsc * xsc;
                float e = exp2f(u * NEG_HALF_L2E);
                acc3 = fmaf((u - 1.0f) * e, wp.z, acc3);
                acc3 = fmaf(xs.y, wp.w, acc3);
            }
        }
    }

    float bscale = bn_g[o] * fast_rsq(bn_v[o] + 1e-5f);
    float bshift = fmaf(-bn_m[o], bscale, bn_b[o]);
    float lg = ln_g[o], lb = ln_b[o];
    float vals[4] = {acc0, acc1, acc2, acc3};
    #pragma unroll
    for (int rr = 0; rr < 4; ++rr) {
        float y = fmaf(vals[rr], bscale, bshift);
        float s = y;
        #pragma unroll
        for (int m = 1; m < 64; m <<= 1) s += __shfl_xor(s, m, 64);
        float mu = s * (1.0f / 64.0f);
        float d = y - mu;
        float s2 = d * d;
        #pragma unroll
        for (int m = 1; m < 64; m <<= 1) s2 += __shfl_xor(s2, m, 64);
        float rstd = fast_rsq(s2 * (1.0f / 64.0f) + 1e-5f);
        x_emb[(row0 + grp * 4 + rr) * 64 + o] = fmaf(d * rstd, lg, lb);
    }
}

// ---------------- K2: gi = x_emb @ w_ih^T + b_ih ----------------
__global__ __launch_bounds__(384) void gi_kernel(
    const float* __restrict__ ws_c,
    const float* __restrict__ bihf, const float* __restrict__ bihb,
    float* __restrict__ gi) {
    __shared__ __align__(16) float xs[32 * 64];   // 8 KB
    const float4* wT4   = (const float4*)(ws_c + WS_WT4);
    const float*  x_emb = ws_c + WS_XEMB;
    int t = threadIdx.x;
    int row0 = blockIdx.x * 32;
    {
        const float4* src = (const float4*)(x_emb + row0 * 64);
        float4* dst = (float4*)xs;
        for (int i = t; i < 512; i += 384) dst[i] = src[i];
    }
    int dir = t / 192, gg = t - dir * 192;
    float bih = dir ? bihb[gg] : bihf[gg];
    float4 w[16];
    #pragma unroll
    for (int k4 = 0; k4 < 16; ++k4) w[k4] = wT4[k4 * 384 + t];
    __syncthreads();
    for (int r = 0; r < 32; r += 2) {
        const float4* x0 = (const float4*)(xs + r * 64);
        const float4* x1 = (const float4*)(xs + r * 64 + 64);
        float a0 = bih, a1 = 0.f, b0 = bih, b1 = 0.f;
        #pragma unroll
        for (int k4 = 0; k4 < 16; k4 += 2) {
            float4 xv = x0[k4];     float4 wv = w[k4];
            a0 = fmaf(xv.x, wv.x, a0); a0 = fmaf(xv.y, wv.y, a0);
            a0 = fmaf(xv.z, wv.z, a0); a0 = fmaf(xv.w, wv.w, a0);
            float4 xu = x0[k4 + 1]; float4 wu = w[k4 + 1];
            a1 = fmaf(xu.x, wu.x, a1); a1 = fmaf(xu.y, wu.y, a1);
            a1 = fmaf(xu.z, wu.z, a1); a1 = fmaf(xu.w, wu.w, a1);
            float4 yv = x1[k4];
            b0 = fmaf(yv.x, wv.x, b0); b0 = fmaf(yv.y, wv.y, b0);
            b0 = fmaf(yv.z, wv.z, b0); b0 = fmaf(yv.w, wv.w, b0);
            float4 yu = x1[k4 + 1];
            b1 = fmaf(yu.x, wu.x, b1); b1 = fmaf(yu.y, wu.y, b1);
            b1 = fmaf(yu.z, wu.z, b1); b1 = fmaf(yu.w, wu.w, b1);
        }
        gi[(row0 + r) * 384 + t]     = a0 + a1;
        gi[(row0 + r + 1) * 384 + t] = b0 + b1;
    }
}

// ---------------- K3: GRU — 2 chains/block, SEQUENTIAL matvecs (spill-safe) ----------------
// 64 blocks: dir = blk>>5, b0=(blk&31)*2, b1=b0+1 (same dir => shared weights).
// Chains computed sequentially so chain A's readlane SGPRs/accs die before
// chain B's start — register pressure ~= R7 (+6). One barrier + one gh
// exchange + one loop tail serves both chains (the amortization win).
// gi staged in 32-step LDS windows, refilled direct global->LDS at boundaries.
__global__ __launch_bounds__(192, 1) void gru_kernel(
    const float* __restrict__ ws_c,
    const float* __restrict__ whhf, const float* __restrict__ bhhf,
    const float* __restrict__ whhb, const float* __restrict__ bhhb,
    float* __restrict__ hc) {
    __shared__ __align__(16) float gi_l[32 * 384];   // 48 KB: [ssl][chain*192 + t]
    __shared__ float gh[2][384];
    const float* gi = ws_c + WS_GI;
    int t = threadIdx.x, lane = t & 63;
    int dir = blockIdx.x >> 5;
    int b0 = (blockIdx.x & 31) * 2, b1 = b0 + 1;
    const float* whh = dir ? whhb : whhf;
    const float* bhh = dir ? bhhb : bhhf;

    float4 w[16];                                  // R5/R7-proven form: 64 VGPRs
    {
        const float4* wrow = (const float4*)(whh + t * 64);
        #pragma unroll
        for (int q = 0; q < 16; ++q) w[q] = wrow[q];
    }
    float bias = bhh[t];

    const float* gsrc0 = gi + (size_t)(b0 * SEQ) * 384 + dir * 192 + t;
    const float* gsrc1 = gi + (size_t)(b1 * SEQ) * 384 + dir * 192 + t;

    // window 0 (steps 0..31) -> LDS
    #pragma unroll 4
    for (int q = 0; q < 32; ++q) {
        int sidx = dir ? (SEQ - 1 - q) : q;
        gi_l[q * 384 + t]       = gsrc0[sidx * 384];
        gi_l[q * 384 + 192 + t] = gsrc1[sidx * 384];
    }
    float h0 = 0.0f, h1 = 0.0f;
    __syncthreads();

    for (int ss = 0; ss < SEQ; ++ss) {
        int ssl = ss & 31;
        if (ss != 0 && ssl == 0) {
            __syncthreads();                       // old-window reads complete
            #pragma unroll 4
            for (int q = 0; q < 32; ++q) {         // direct global->LDS refill
                int s_it = ss + q;
                int sidx = dir ? (SEQ - 1 - s_it) : s_it;
                gi_l[q * 384 + t]       = gsrc0[sidx * 384];
                gi_l[q * 384 + 192 + t] = gsrc1[sidx * 384];
            }
            __syncthreads();                       // refill visible
        }
        // ---- chain A matvec (complete before B: bounded live ranges) ----
        float a0 = bias, a1 = 0.f, a2 = 0.f, a3 = 0.f;
        #pragma unroll
        for (int q = 0; q < 16; ++q) {
            float x0 = readlane_f(h0, 4 * q);
            float x1 = readlane_f(h0, 4 * q + 1);
            float x2 = readlane_f(h0, 4 * q + 2);
            float x3 = readlane_f(h0, 4 * q + 3);
            float4 wv = w[q];
            a0 = fmaf(wv.x, x0, a0);
            a1 = fmaf(wv.y, x1, a1);
            a2 = fmaf(wv.z, x2, a2);
            a3 = fmaf(wv.w, x3, a3);
        }
        gh[ss & 1][t] = (a0 + a1) + (a2 + a3);
        // ---- chain B matvec ----
        float c0 = bias, c1 = 0.f, c2 = 0.f, c3 = 0.f;
        #pragma unroll
        for (int q = 0; q < 16; ++q) {
            float y0 = readlane_f(h1, 4 * q);
            float y1 = readlane_f(h1, 4 * q + 1);
            float y2 = readlane_f(h1, 4 * q + 2);
            float y3 = readlane_f(h1, 4 * q + 3);
            float4 wv = w[q];
            c0 = fmaf(wv.x, y0, c0);
            c1 = fmaf(wv.y, y1, c1);
            c2 = fmaf(wv.z, y2, c2);
            c3 = fmaf(wv.w, y3, c3);
        }
        int pp = ss & 1;
        gh[pp][192 + t] = (c0 + c1) + (c2 + c3);
        // consumer-side gi reads hoisted before the barrier (window only
        // mutated across barrier-separated refills)
        float ir0 = gi_l[ssl * 384 + lane];
        float iz0 = gi_l[ssl * 384 + 64 + lane];
        float in0 = gi_l[ssl * 384 + 128 + lane];
        float ir1 = gi_l[ssl * 384 + 192 + lane];
        float iz1 = gi_l[ssl * 384 + 256 + lane];
        float in1 = gi_l[ssl * 384 + 320 + lane];
        __syncthreads();
        float r0 = sigmoid_(ir0 + gh[pp][lane]);
        float z0 = sigmoid_(iz0 + gh[pp][64 + lane]);
        float n0 = tanh_(fmaf(r0, gh[pp][128 + lane], in0));
        h0 = fmaf(z0, h0 - n0, n0);
        float r1 = sigmoid_(ir1 + gh[pp][192 + lane]);
        float z1 = sigmoid_(iz1 + gh[pp][256 + lane]);
        float n1 = tanh_(fmaf(r1, gh[pp][320 + lane], in1));
        h1 = fmaf(z1, h1 - n1, n1);
    }
    if (t < 64) {
        hc[b0 * 128 + dir * 64 + lane] = h0;
        hc[b1 * 128 + dir * 64 + lane] = h1;
    }
}

// ---------------- K4: classifier head ----------------
__global__ __launch_bounds__(64) void head_kernel(
    const float* __restrict__ ws_c,
    const float* __restrict__ fc1w, const float* __restrict__ fc1b,
    const float* __restrict__ fc2w, const float* __restrict__ fc2b,
    float* __restrict__ out) {
    __shared__ __align__(16) float hr[128];
    __shared__ float h1[64];
    const float* hc = ws_c + WS_HC;
    int bb = blockIdx.x, t = threadIdx.x;
    hr[t]      = hc[bb * 128 + t];
    hr[64 + t] = hc[bb * 128 + 64 + t];
    __syncthreads();
    float acc = fc1b[t];
    const float4* w4 = (const float4*)(fc1w + t * 128);
    const float4* h4 = (const float4*)hr;
    #pragma unroll 8
    for (int k4 = 0; k4 < 32; ++k4) {
        float4 wv = w4[k4]; float4 hv = h4[k4];
        acc = fmaf(hv.x, wv.x, acc); acc = fmaf(hv.y, wv.y, acc);
        acc = fmaf(hv.z, wv.z, acc); acc = fmaf(hv.w, wv.w, acc);
    }
    h1[t] = fmaxf(acc, 0.0f);
    __syncthreads();
    if (t < NCLS) {
        float acc2 = fc2b[t];
        const float* wr = fc2w + t * 64;
        #pragma unroll 8
        for (int k = 0; k < 64; ++k) acc2 = fmaf(h1[k], wr[k], acc2);
        out[bb * NCLS + t] = acc2;
    }
}

extern "C" void kernel_launch(void* const* d_in, const int* in_sizes, int n_in,
                              void* d_out, int out_size, void* d_ws, size_t ws_size,
                              hipStream_t stream) {
    const float* x_seq = (const float*)d_in[0];
    const float* wscal = (const float*)d_in[1];
    const float* wtran = (const float*)d_in[2];
    const float* wwght = (const float*)d_in[3];
    const float* bwght = (const float*)d_in[4];
    const float* bn_g  = (const float*)d_in[5];
    const float* bn_b  = (const float*)d_in[6];
    const float* bn_m  = (const float*)d_in[7];
    const float* bn_v  = (const float*)d_in[8];
    const float* ln_g  = (const float*)d_in[9];
    const float* ln_b  = (const float*)d_in[10];
    const float* wihf  = (const float*)d_in[11];
    const float* whhf  = (const float*)d_in[12];
    const float* bihf  = (const float*)d_in[13];
    const float* bhhf  = (const float*)d_in[14];
    const float* wihb  = (const float*)d_in[15];
    const float* whhb  = (const float*)d_in[16];
    const float* bihb  = (const float*)d_in[17];
    const float* bhhb  = (const float*)d_in[18];
    const float* fc1w  = (const float*)d_in[19];
    const float* fc1b  = (const float*)d_in[20];
    const float* fc2w  = (const float*)d_in[21];
    const float* fc2b  = (const float*)d_in[22];
    float* ws  = (float*)d_ws;
    float* out = (float*)d_out;

    hipMemsetAsync(ws + WS_FLAG, 0, sizeof(int), stream);
    hipLaunchKernelGGL(prep_kernel, dim3(186), dim3(256), 0, stream,
                       wscal, wtran, wwght, bwght, wihf, wihb, ws);
    hipLaunchKernelGGL(wavkan_kernel, dim3(NROWS / 16), dim3(256), 0, stream,
                       x_seq, bn_g, bn_b, bn_m, bn_v, ln_g, ln_b, ws, ws + WS_XEMB);
    hipLaunchKernelGGL(gi_kernel, dim3(NROWS / 32), dim3(384), 0, stream,
                       ws, bihf, bihb, ws + WS_GI);
    hipLaunchKernelGGL(gru_kernel, dim3(64), dim3(192), 0, stream,
                       ws, whhf, bhhf, whhb, bhhb, ws + WS_HC);
    hipLaunchKernelGGL(head_kernel, dim3(64), dim3(64), 0, stream,
                       ws, fc1w, fc1b, fc2w, fc2b, out);
}

// Round 12
// 226.016 us; speedup vs baseline: 1.7791x; 1.2384x over previous
//
#include <hip/hip_runtime.h>

#define IN_F   360
#define HIDN   64
#define NCLS   5
#define BATCH  64
#define SEQ    128
#define NROWS  (BATCH*SEQ)   // 8192

// workspace layout (float offsets)
#define WS_FLAG  0            // int flag: 0 => scale==1 && trans==0 everywhere (fast path ok)
#define WS_WPACK 16           // float4[360*64] = 92160 floats (general path)
#define WS_WFAST 92176        // float2[360*64] = 46080 floats (fast path packed {C*ww, bw})
#define WS_WT4   138256       // 24576 floats (w_ih transposed, float4-packed)
#define WS_XEMB  162832       // 8192*64 = 524288
#define WS_GI    687120       // 8192*384 = 3145728
#define WS_HC    3832848      // 64*128 = 8192

#define LOG2E        1.4426950408889634f
#define NEG_HALF_L2E (-0.7213475204444817f)

__device__ __forceinline__ float fast_rcp(float x) { return __builtin_amdgcn_rcpf(x); }
__device__ __forceinline__ float fast_rsq(float x) { return __builtin_amdgcn_rsqf(x); }
__device__ __forceinline__ float sigmoid_(float x) {
    x = fminf(fmaxf(x, -60.0f), 60.0f);
    return fast_rcp(1.0f + exp2f(-LOG2E * x));
}
__device__ __forceinline__ float tanh_(float x) {
    x = fminf(fmaxf(x, -30.0f), 30.0f);
    float e = exp2f(-2.8853900817779268f * x);   // e^{-2x}
    return (1.0f - e) * fast_rcp(1.0f + e);
}
// CRITICAL: __builtin_amdgcn_readlane is (int,int) — passing a float would
// NUMERICALLY convert (R4/R6 bug). Bit-cast in and out.
__device__ __forceinline__ float readlane_f(float v, int l) {
    return __int_as_float(__builtin_amdgcn_readlane(__float_as_int(v), l));
}

// ---------------- K0: weight prep + fast-path eligibility check ----------------
__global__ __launch_bounds__(256) void prep_kernel(
    const float* __restrict__ scale, const float* __restrict__ trans,
    const float* __restrict__ ww,    const float* __restrict__ bw,
    const float* __restrict__ wihf,  const float* __restrict__ wihb,
    float* __restrict__ ws) {
    int idx = blockIdx.x * 256 + threadIdx.x;
    float4* wpack  = (float4*)(ws + WS_WPACK);
    float2* wfast2 = (float2*)(ws + WS_WFAST);
    float*  wT4    = ws + WS_WT4;
    int*    flagp  = (int*)(ws + WS_FLAG);
    if (idx < 64 * IN_F) {
        int o = idx & 63, i = idx >> 6;
        float s  = scale[o * IN_F + i];
        float tr = trans[o * IN_F + i];
        if (s != 1.0f || tr != 0.0f) atomicOr(flagp, 1);
        float a  = 1.0f / s;
        float b  = -tr * a;
        float wq = 0.8673250705840776f * ww[o * IN_F + i];   // 2/(sqrt(3)*pi^0.25)
        float bb = bw[o * IN_F + i];
        wpack[i * 64 + o] = make_float4(a, b, wq, bb);
        wfast2[(i >> 1) * 128 + o * 2 + (i & 1)] = make_float2(wq, bb);
    }
    int idx2 = idx - 64 * IN_F;
    if (idx2 >= 0 && idx2 < 24576) {
        int e = idx2 & 3; int rest = idx2 >> 2;
        int g = rest % 384; int k4 = rest / 384;
        int k = k4 * 4 + e; int dir = g / 192; int gg = g - dir * 192;
        const float* src = dir ? wihb : wihf;
        wT4[idx2] = src[gg * 64 + k];
    }
}

// ---------------- K1: WavKAN + BatchNorm + LayerNorm ----------------
__global__ __launch_bounds__(256) void wavkan_kernel(
    const float* __restrict__ x_seq,
    const float* __restrict__ bn_g, const float* __restrict__ bn_b,
    const float* __restrict__ bn_m, const float* __restrict__ bn_v,
    const float* __restrict__ ln_g, const float* __restrict__ ln_b,
    const float* __restrict__ ws_c, float* __restrict__ x_emb) {
    __shared__ float2 xs_lds[16 * IN_F];   // 46 KB
    int t = threadIdx.x;
    int row0 = blockIdx.x * 16;
    int o = t & 63, grp = t >> 6;
    int fast = (*(const int*)(ws_c + WS_FLAG)) == 0;

    float acc0 = 0.f, acc1 = 0.f, acc2 = 0.f, acc3 = 0.f;

    if (fast) {
        for (int idx = t; idx < 16 * IN_F; idx += 256) {
            int r = idx / IN_F, i = idx - r * IN_F;
            float x = x_seq[(row0 + r) * IN_F + i];
            float u = x * x;
            float phi = (u - 1.0f) * exp2f(u * NEG_HALF_L2E);
            float sl  = x * fast_rcp(1.0f + exp2f(-LOG2E * x));
            xs_lds[idx] = make_float2(phi, sl);
        }
        __syncthreads();
        const float4* wf4 = (const float4*)(ws_c + WS_WFAST);
        const float4* xs4 = (const float4*)xs_lds;
        const float4* xr0 = xs4 + (grp * 4 + 0) * 180;
        const float4* xr1 = xs4 + (grp * 4 + 1) * 180;
        const float4* xr2 = xs4 + (grp * 4 + 2) * 180;
        const float4* xr3 = xs4 + (grp * 4 + 3) * 180;
        #pragma unroll 2
        for (int i2 = 0; i2 < 180; ++i2) {
            float4 wp = wf4[i2 * 64 + o];
            float4 a = xr0[i2];
            acc0 = fmaf(a.x, wp.x, acc0); acc0 = fmaf(a.y, wp.y, acc0);
            acc0 = fmaf(a.z, wp.z, acc0); acc0 = fmaf(a.w, wp.w, acc0);
            float4 b = xr1[i2];
            acc1 = fmaf(b.x, wp.x, acc1); acc1 = fmaf(b.y, wp.y, acc1);
            acc1 = fmaf(b.z, wp.z, acc1); acc1 = fmaf(b.w, wp.w, acc1);
            float4 c = xr2[i2];
            acc2 = fmaf(c.x, wp.x, acc2); acc2 = fmaf(c.y, wp.y, acc2);
            acc2 = fmaf(c.z, wp.z, acc2); acc2 = fmaf(c.w, wp.w, acc2);
            float4 d = xr3[i2];
            acc3 = fmaf(d.x, wp.x, acc3); acc3 = fmaf(d.y, wp.y, acc3);
            acc3 = fmaf(d.z, wp.z, acc3); acc3 = fmaf(d.w, wp.w, acc3);
        }
    } else {
        for (int idx = t; idx < 16 * IN_F; idx += 256) {
            int r = idx / IN_F, i = idx - r * IN_F;
            float x = x_seq[(row0 + r) * IN_F + i];
            float sl = x * fast_rcp(1.0f + exp2f(-LOG2E * x));
            xs_lds[idx] = make_float2(x, sl);
        }
        __syncthreads();
        const float4* wpack = (const float4*)(ws_c + WS_WPACK);
        const float2* xr0 = xs_lds + (grp * 4 + 0) * IN_F;
        const float2* xr1 = xs_lds + (grp * 4 + 1) * IN_F;
        const float2* xr2 = xs_lds + (grp * 4 + 2) * IN_F;
        const float2* xr3 = xs_lds + (grp * 4 + 3) * IN_F;
        for (int i = 0; i < IN_F; ++i) {
            float4 wp = wpack[i * 64 + o];
            {
                float2 xs = xr0[i];
                float xsc = fmaf(xs.x, wp.x, wp.y); float u = xsc * xsc;
                float e = exp2f(u * NEG_HALF_L2E);
                acc0 = fmaf((u - 1.0f) * e, wp.z, acc0);
                acc0 = fmaf(xs.y, wp.w, acc0);
            }
            {
                float2 xs = xr1[i];
                float xsc = fmaf(xs.x, wp.x, wp.y); float u = xsc * xsc;
                float e = exp2f(u * NEG_HALF_L2E);
                acc1 = fmaf((u - 1.0f) * e, wp.z, acc1);
                acc1 = fmaf(xs.y, wp.w, acc1);
            }
            {
                float2 xs = xr2[i];
                float xsc = fmaf(xs.x, wp.x, wp.y); float u = xsc * xsc;
                float e = exp2f(u * NEG_HALF_L2E);
                acc2 = fmaf((u - 1.0f) * e, wp.z, acc2);
                acc2 = fmaf(xs.y, wp.w, acc2);
            }
            {
                float2 xs = xr3[i];
                float xsc = fmaf(xs.x, wp.x, wp.y); float u = xsc * xsc;
                float e = exp2f(u * NEG_HALF_L2E);
                acc3 = fmaf((u - 1.0f) * e, wp.z, acc3);
                acc3 = fmaf(xs.y, wp.w, acc3);
            }
        }
    }

    float bscale = bn_g[o] * fast_rsq(bn_v[o] + 1e-5f);
    float bshift = fmaf(-bn_m[o], bscale, bn_b[o]);
    float lg = ln_g[o], lb = ln_b[o];
    float vals[4] = {acc0, acc1, acc2, acc3};
    #pragma unroll
    for (int rr = 0; rr < 4; ++rr) {
        float y = fmaf(vals[rr], bscale, bshift);
        float s = y;
        #pragma unroll
        for (int m = 1; m < 64; m <<= 1) s += __shfl_xor(s, m, 64);
        float mu = s * (1.0f / 64.0f);
        float d = y - mu;
        float s2 = d * d;
        #pragma unroll
        for (int m = 1; m < 64; m <<= 1) s2 += __shfl_xor(s2, m, 64);
        float rstd = fast_rsq(s2 * (1.0f / 64.0f) + 1e-5f);
        x_emb[(row0 + grp * 4 + rr) * 64 + o] = fmaf(d * rstd, lg, lb);
    }
}

// ---------------- K2: gi = x_emb @ w_ih^T + b_ih ----------------
__global__ __launch_bounds__(384) void gi_kernel(
    const float* __restrict__ ws_c,
    const float* __restrict__ bihf, const float* __restrict__ bihb,
    float* __restrict__ gi) {
    __shared__ __align__(16) float xs[32 * 64];   // 8 KB
    const float4* wT4   = (const float4*)(ws_c + WS_WT4);
    const float*  x_emb = ws_c + WS_XEMB;
    int t = threadIdx.x;
    int row0 = blockIdx.x * 32;
    {
        const float4* src = (const float4*)(x_emb + row0 * 64);
        float4* dst = (float4*)xs;
        for (int i = t; i < 512; i += 384) dst[i] = src[i];
    }
    int dir = t / 192, gg = t - dir * 192;
    float bih = dir ? bihb[gg] : bihf[gg];
    float4 w[16];
    #pragma unroll
    for (int k4 = 0; k4 < 16; ++k4) w[k4] = wT4[k4 * 384 + t];
    __syncthreads();
    for (int r = 0; r < 32; r += 2) {
        const float4* x0 = (const float4*)(xs + r * 64);
        const float4* x1 = (const float4*)(xs + r * 64 + 64);
        float a0 = bih, a1 = 0.f, b0 = bih, b1 = 0.f;
        #pragma unroll
        for (int k4 = 0; k4 < 16; k4 += 2) {
            float4 xv = x0[k4];     float4 wv = w[k4];
            a0 = fmaf(xv.x, wv.x, a0); a0 = fmaf(xv.y, wv.y, a0);
            a0 = fmaf(xv.z, wv.z, a0); a0 = fmaf(xv.w, wv.w, a0);
            float4 xu = x0[k4 + 1]; float4 wu = w[k4 + 1];
            a1 = fmaf(xu.x, wu.x, a1); a1 = fmaf(xu.y, wu.y, a1);
            a1 = fmaf(xu.z, wu.z, a1); a1 = fmaf(xu.w, wu.w, a1);
            float4 yv = x1[k4];
            b0 = fmaf(yv.x, wv.x, b0); b0 = fmaf(yv.y, wv.y, b0);
            b0 = fmaf(yv.z, wv.z, b0); b0 = fmaf(yv.w, wv.w, b0);
            float4 yu = x1[k4 + 1];
            b1 = fmaf(yu.x, wu.x, b1); b1 = fmaf(yu.y, wu.y, b1);
            b1 = fmaf(yu.z, wu.z, b1); b1 = fmaf(yu.w, wu.w, b1);
        }
        gi[(row0 + r) * 384 + t]     = a0 + a1;
        gi[(row0 + r + 1) * 384 + t] = b0 + b1;
    }
}

// ---------------- K3: bidirectional GRU recurrence (R7 verbatim — best known) ----------------
// 128 blocks = (b,dir); 192 threads; thread t owns W_hh row t in 64 scalar VGPRs
// (held resident: NO global loads inside the loop — preload-only, the one shape
// the allocator keeps registers for). gi: steps 0..63 in 48KB LDS, 64..127 in
// pf[64] regs dumped at the phase boundary. h broadcast via readlane from
// registers (hreg identical in all 3 waves); 1 barrier/step.
__global__ __launch_bounds__(192, 1) void gru_kernel(
    const float* __restrict__ ws_c,
    const float* __restrict__ whhf, const float* __restrict__ bhhf,
    const float* __restrict__ whhb, const float* __restrict__ bhhb,
    float* __restrict__ hc) {
    __shared__ __align__(16) float gi_l[64 * 192];   // 48 KB, [step][gate-float]
    __shared__ float gh[2][192];
    const float* gi = ws_c + WS_GI;
    int t = threadIdx.x, lane = t & 63;
    int b = blockIdx.x & 63, dir = blockIdx.x >> 6;
    const float* whh = dir ? whhb : whhf;
    const float* bhh = dir ? bhhb : bhhf;

    float w[64];
    {
        const float4* wrow = (const float4*)(whh + t * 64);
        #pragma unroll
        for (int q = 0; q < 16; ++q) {
            float4 a = wrow[q];
            w[4*q] = a.x; w[4*q+1] = a.y; w[4*q+2] = a.z; w[4*q+3] = a.w;
        }
    }
    float bias = bhh[t];

    const float* gsrc = gi + (size_t)(b * SEQ) * 384 + dir * 192 + t;
    #pragma unroll
    for (int q = 0; q < 64; ++q) {
        int sidx = dir ? (SEQ - 1 - q) : q;
        gi_l[q * 192 + t] = gsrc[sidx * 384];
    }
    float pf[64];
    #pragma unroll
    for (int q = 0; q < 64; ++q) {
        int sidx = dir ? (SEQ - 1 - (64 + q)) : (64 + q);
        pf[q] = gsrc[sidx * 384];
    }
    float hreg = 0.0f;
    __syncthreads();

    for (int ss = 0; ss < SEQ; ++ss) {
        if (ss == 64) {
            __syncthreads();                       // phase-1 reads complete
            #pragma unroll
            for (int q = 0; q < 64; ++q) gi_l[q * 192 + t] = pf[q];
            __syncthreads();                       // refill visible
        }
        int ssl = ss & 63;
        float a0 = bias, a1 = 0.f, a2 = 0.f, a3 = 0.f;
        #pragma unroll
        for (int k = 0; k < 64; k += 4) {
            float h0 = readlane_f(hreg, k);
            float h1 = readlane_f(hreg, k + 1);
            float h2 = readlane_f(hreg, k + 2);
            float h3 = readlane_f(hreg, k + 3);
            a0 = fmaf(w[k],     h0, a0);
            a1 = fmaf(w[k + 1], h1, a1);
            a2 = fmaf(w[k + 2], h2, a2);
            a3 = fmaf(w[k + 3], h3, a3);
        }
        int p = ss & 1;
        gh[p][t] = (a0 + a1) + (a2 + a3);
        float ir  = gi_l[ssl * 192 + lane];
        float iz  = gi_l[ssl * 192 + 64 + lane];
        float in_ = gi_l[ssl * 192 + 128 + lane];
        __syncthreads();
        float r = sigmoid_(ir + gh[p][lane]);
        float z = sigmoid_(iz + gh[p][64 + lane]);
        float n = tanh_(fmaf(r, gh[p][128 + lane], in_));
        hreg = fmaf(z, hreg - n, n);               // (1-z)*n + z*h, same in all waves
    }
    if (t < 64) hc[b * 128 + dir * 64 + lane] = hreg;
}

// ---------------- K4: classifier head ----------------
__global__ __launch_bounds__(64) void head_kernel(
    const float* __restrict__ ws_c,
    const float* __restrict__ fc1w, const float* __restrict__ fc1b,
    const float* __restrict__ fc2w, const float* __restrict__ fc2b,
    float* __restrict__ out) {
    __shared__ __align__(16) float hr[128];
    __shared__ float h1[64];
    const float* hc = ws_c + WS_HC;
    int bb = blockIdx.x, t = threadIdx.x;
    hr[t]      = hc[bb * 128 + t];
    hr[64 + t] = hc[bb * 128 + 64 + t];
    __syncthreads();
    float acc = fc1b[t];
    const float4* w4 = (const float4*)(fc1w + t * 128);
    const float4* h4 = (const float4*)hr;
    #pragma unroll 8
    for (int k4 = 0; k4 < 32; ++k4) {
        float4 wv = w4[k4]; float4 hv = h4[k4];
        acc = fmaf(hv.x, wv.x, acc); acc = fmaf(hv.y, wv.y, acc);
        acc = fmaf(hv.z, wv.z, acc); acc = fmaf(hv.w, wv.w, acc);
    }
    h1[t] = fmaxf(acc, 0.0f);
    __syncthreads();
    if (t < NCLS) {
        float acc2 = fc2b[t];
        const float* wr = fc2w + t * 64;
        #pragma unroll 8
        for (int k = 0; k < 64; ++k) acc2 = fmaf(h1[k], wr[k], acc2);
        out[bb * NCLS + t] = acc2;
    }
}

extern "C" void kernel_launch(void* const* d_in, const int* in_sizes, int n_in,
                              void* d_out, int out_size, void* d_ws, size_t ws_size,
                              hipStream_t stream) {
    const float* x_seq = (const float*)d_in[0];
    const float* wscal = (const float*)d_in[1];
    const float* wtran = (const float*)d_in[2];
    const float* wwght = (const float*)d_in[3];
    const float* bwght = (const float*)d_in[4];
    const float* bn_g  = (const float*)d_in[5];
    const float* bn_b  = (const float*)d_in[6];
    const float* bn_m  = (const float*)d_in[7];
    const float* bn_v  = (const float*)d_in[8];
    const float* ln_g  = (const float*)d_in[9];
    const float* ln_b  = (const float*)d_in[10];
    const float* wihf  = (const float*)d_in[11];
    const float* whhf  = (const float*)d_in[12];
    const float* bihf  = (const float*)d_in[13];
    const float* bhhf  = (const float*)d_in[14];
    const float* wihb  = (const float*)d_in[15];
    const float* whhb  = (const float*)d_in[16];
    const float* bihb  = (const float*)d_in[17];
    const float* bhhb  = (const float*)d_in[18];
    const float* fc1w  = (const float*)d_in[19];
    const float* fc1b  = (const float*)d_in[20];
    const float* fc2w  = (const float*)d_in[21];
    const float* fc2b  = (const float*)d_in[22];
    float* ws  = (float*)d_ws;
    float* out = (float*)d_out;

    hipMemsetAsync(ws + WS_FLAG, 0, sizeof(int), stream);
    hipLaunchKernelGGL(prep_kernel, dim3(186), dim3(256), 0, stream,
                       wscal, wtran, wwght, bwght, wihf, wihb, ws);
    hipLaunchKernelGGL(wavkan_kernel, dim3(NROWS / 16), dim3(256), 0, stream,
                       x_seq, bn_g, bn_b, bn_m, bn_v, ln_g, ln_b, ws, ws + WS_XEMB);
    hipLaunchKernelGGL(gi_kernel, dim3(NROWS / 32), dim3(384), 0, stream,
                       ws, bihf, bihb, ws + WS_GI);
    hipLaunchKernelGGL(gru_kernel, dim3(128), dim3(192), 0, stream,
                       ws, whhf, bhhf, whhb, bhhb, ws + WS_HC);
    hipLaunchKernelGGL(head_kernel, dim3(64), dim3(64), 0, stream,
                       ws, fc1w, fc1b, fc2w, fc2b, out);
}